// Round 1
// baseline (213.508 us; speedup 1.0000x reference)
//
#include <hip/hip_runtime.h>
#include <hip/hip_fp16.h>

typedef _Float16 f16;
typedef unsigned int u32;
typedef _Float16 f16x8 __attribute__((ext_vector_type(8)));
typedef float f32x4 __attribute__((ext_vector_type(4)));

#define B_  2
#define N_  2048
#define C_  1024
#define H_  16
#define HD_ 64

// ---------------------------------------------------------------- helpers
__device__ __forceinline__ void gload_lds16(const void* g, void* l) {
  __builtin_amdgcn_global_load_lds((const __attribute__((address_space(1))) u32*)g,
                                   (__attribute__((address_space(3))) u32*)l,
                                   16, 0, 0);
}

// ---------------------------------------------------------------- mask dtype probe
// rope_mask may arrive as int32 / float32 (4-byte) or bool (1-byte). Scan the
// first 1024 words: if every word is {0,1,0x3F800000} -> 4-byte elements,
// else -> byte elements. (Packed bools make "mixed" words with prob ~1.)
__global__ void detect_mask(const u32* __restrict__ m, int* __restrict__ flag) {
  __shared__ int bad;
  if (threadIdx.x == 0) bad = 0;
  __syncthreads();
  int v = 0;
  for (int i = threadIdx.x; i < 1024; i += 256) {
    u32 w = m[i];
    if (w != 0u && w != 1u && w != 0x3F800000u) v = 1;
  }
  if (v) atomicOr(&bad, 1);
  __syncthreads();
  if (threadIdx.x == 0) *flag = bad;   // 1 => byte mask, 0 => 4-byte mask
}

// ---------------------------------------------------------------- x f32 -> f16
__global__ __launch_bounds__(256) void cvt_x(const float* __restrict__ in,
                                             f16* __restrict__ out, int n8) {
  const int i = blockIdx.x * 256 + threadIdx.x;
  if (i >= n8) return;
  const float4 a = ((const float4*)in)[i * 2];
  const float4 b = ((const float4*)in)[i * 2 + 1];
  f16x8 o = {(f16)a.x, (f16)a.y, (f16)a.z, (f16)a.w,
             (f16)b.x, (f16)b.y, (f16)b.z, (f16)b.w};
  ((f16x8*)out)[i] = o;
}

// ---------------------------------------------------------------- W (RxC f32) -> Wt (CxR f16)
__global__ __launch_bounds__(256) void transpose_cvt(const float* __restrict__ W,
                                                     f16* __restrict__ Wt,
                                                     int R, int Ccols) {
  __shared__ __align__(16) f16 tile[32][34];
  const int c0 = blockIdx.x * 32, r0 = blockIdx.y * 32;
  const int tx = threadIdx.x, ty = threadIdx.y;  // 32 x 8
#pragma unroll
  for (int k = 0; k < 4; ++k)
    tile[ty + 8 * k][tx] = (f16)W[(size_t)(r0 + ty + 8 * k) * Ccols + c0 + tx];
  __syncthreads();
#pragma unroll
  for (int k = 0; k < 4; ++k)
    Wt[(size_t)(c0 + ty + 8 * k) * R + r0 + tx] = tile[tx][ty + 8 * k];
}

// ---------------------------------------------------------------- GEMM  C = A(MxK) * Bt(NxK)^T + bias
// 128x128 tile, BK=64, 4 waves (2x2), 4x4 16x16x32 frags/wave.
// LDS linear dest for global_load_lds; XOR chunk swizzle applied on the global
// source and on the LDS read (same involution) -> 2-way-max bank aliasing.
template <bool OUT_F32>
__global__ __launch_bounds__(256) void gemm_bt(const f16* __restrict__ A,
                                               const f16* __restrict__ Bt,
                                               const float* __restrict__ bias,
                                               void* __restrict__ Cout,
                                               int M, int N, int K) {
  __shared__ __align__(16) f16 As[128 * 64];
  __shared__ __align__(16) f16 Bs[128 * 64];
  const int tid = threadIdx.x;
  const int lane = tid & 63;
  const int wv = tid >> 6;
  const int wm = wv >> 1, wn = wv & 1;
  const int nTN = N >> 7;
  const int tM = blockIdx.x / nTN, tN = blockIdx.x % nTN;
  const int rowBase = tM << 7, colBase = tN << 7;
  const int cl = lane & 15, cg = lane >> 4;

  f32x4 acc[4][4];
#pragma unroll
  for (int i = 0; i < 4; ++i)
#pragma unroll
    for (int j = 0; j < 4; ++j) acc[i][j] = (f32x4){0.f, 0.f, 0.f, 0.f};

  const int sR = tid >> 3, sC = tid & 7;

  for (int k0 = 0; k0 < K; k0 += 64) {
#pragma unroll
    for (int is = 0; is < 4; ++is) {
      const int r = is * 32 + sR;
      const int sc = sC ^ (r & 7);
      gload_lds16(A + (size_t)(rowBase + r) * K + k0 + sc * 8, As + is * 2048 + tid * 8);
    }
#pragma unroll
    for (int is = 0; is < 4; ++is) {
      const int r = is * 32 + sR;
      const int sc = sC ^ (r & 7);
      gload_lds16(Bt + (size_t)(colBase + r) * K + k0 + sc * 8, Bs + is * 2048 + tid * 8);
    }
    asm volatile("s_waitcnt vmcnt(0)" ::: "memory");
    __syncthreads();

#pragma unroll
    for (int ks = 0; ks < 2; ++ks) {
      f16x8 af[4], bf[4];
#pragma unroll
      for (int m = 0; m < 4; ++m) {
        const int row = wm * 64 + m * 16 + cl;
        const int ck = (ks * 4 + cg) ^ (row & 7);
        af[m] = *(const f16x8*)(As + row * 64 + ck * 8);
      }
#pragma unroll
      for (int n = 0; n < 4; ++n) {
        const int row = wn * 64 + n * 16 + cl;
        const int ck = (ks * 4 + cg) ^ (row & 7);
        bf[n] = *(const f16x8*)(Bs + row * 64 + ck * 8);
      }
#pragma unroll
      for (int m = 0; m < 4; ++m)
#pragma unroll
        for (int n = 0; n < 4; ++n)
          acc[m][n] = __builtin_amdgcn_mfma_f32_16x16x32_f16(af[m], bf[n], acc[m][n], 0, 0, 0);
    }
    __syncthreads();
  }

#pragma unroll
  for (int m = 0; m < 4; ++m) {
#pragma unroll
    for (int n = 0; n < 4; ++n) {
      const int gr0 = rowBase + wm * 64 + m * 16 + cg * 4;
      const int gc = colBase + wn * 64 + n * 16 + cl;
      const float bz = bias[gc];
#pragma unroll
      for (int reg = 0; reg < 4; ++reg) {
        const float v = acc[m][n][reg] + bz;
        if (OUT_F32)
          ((float*)Cout)[(size_t)(gr0 + reg) * N + gc] = v;
        else
          ((f16*)Cout)[(size_t)(gr0 + reg) * N + gc] = (f16)v;
      }
    }
  }
}

// ---------------------------------------------------------------- RoPE + split
// qkv (b,n,[3][H][64]) f16 -> Qh/Kh [b,h,n,64] (rope+mask applied), Vt [b,h,64,n].
// grid: b(2) * ntile(32) * headgroup(4) = 256 blocks, 256 thr.
__global__ __launch_bounds__(256) void rope_split(const f16* __restrict__ qkv,
                                                  const float* __restrict__ px,
                                                  const float* __restrict__ py,
                                                  const float* __restrict__ psp,
                                                  const void* __restrict__ maskPtr,
                                                  const int* __restrict__ maskFlag,
                                                  f16* __restrict__ Qh,
                                                  f16* __restrict__ Kh,
                                                  f16* __restrict__ Vt) {
  __shared__ float cs[64][32], sn[64][32];
  __shared__ __align__(16) f16 vtile[64][72];
  const int tid = threadIdx.x;
  const int blk = blockIdx.x;
  const int hg = blk & 3;
  const int nt = (blk >> 2) & 31;
  const int b = blk >> 7;
  const int n0 = nt * 64;
  const int byteMode = *maskFlag;

  for (int i = tid; i < 64 * 32; i += 256) {
    const int tk = i >> 5, j = i & 31;
    const int n = n0 + tk;
    float ph;
    if (j < 12)      ph = px[((size_t)b * N_ + n) * 12 + j];
    else if (j < 24) ph = py[((size_t)b * N_ + n) * 12 + (j - 12)];
    else             ph = psp[((size_t)b * N_ + n) * 8 + (j - 24)];
    cs[tk][j] = __cosf(ph);
    sn[tk][j] = __sinf(ph);
  }
  __syncthreads();

  const int tk = tid >> 2, hl = tid & 3;
  const int h = hg * 4 + hl;
  const int n = n0 + tk;
  const size_t midx = (size_t)b * N_ + n;
  const bool doRope = byteMode ? (((const unsigned char*)maskPtr)[midx] != 0)
                               : (((const u32*)maskPtr)[midx] != 0u);
  const size_t inRow = ((size_t)b * N_ + n) * 3072 + (size_t)h * 64;
  const size_t outRow = (((size_t)(b * H_ + h)) * N_ + n) * 64;

#pragma unroll
  for (int sec = 0; sec < 2; ++sec) {
    const f16* src = qkv + inRow + sec * 1024;
    float t[64];
#pragma unroll
    for (int c = 0; c < 8; ++c) {
      f16x8 v = *(const f16x8*)(src + c * 8);
#pragma unroll
      for (int j = 0; j < 8; ++j) t[c * 8 + j] = (float)v[j];
    }
    __align__(16) f16 o[64];
    if (doRope) {
#pragma unroll
      for (int d = 0; d < 64; ++d) {
        int j;
        float rot;
        if (d < 24) {
          j = (d < 12) ? d : d - 12;
          rot = (d < 12) ? -t[d + 12] : t[d - 12];
        } else if (d < 48) {
          const int dd = d - 24;
          j = 12 + ((dd < 12) ? dd : dd - 12);
          rot = (dd < 12) ? -t[d + 12] : t[d - 12];
        } else {
          const int dd = d - 48;
          j = 24 + ((dd < 8) ? dd : dd - 8);
          rot = (dd < 8) ? -t[d + 8] : t[d - 8];
        }
        o[d] = (f16)(t[d] * cs[tk][j] + rot * sn[tk][j]);
      }
    } else {
#pragma unroll
      for (int d = 0; d < 64; ++d) o[d] = (f16)t[d];
    }
    f16* dst = (sec == 0 ? Qh : Kh) + outRow;
#pragma unroll
    for (int c = 0; c < 8; ++c) *(f16x8*)(dst + c * 8) = *(const f16x8*)(o + c * 8);
  }

  // V: per head, LDS-transpose a 64x64 tile so Vt writes are 32B-contiguous.
  for (int hl2 = 0; hl2 < 4; ++hl2) {
    const int h2 = hg * 4 + hl2;
    __syncthreads();
    {
      const int tk2 = tid >> 2, c2 = tid & 3;
      const size_t srow = ((size_t)b * N_ + n0 + tk2) * 3072 + 2048 + (size_t)h2 * 64 + c2 * 16;
      *(f16x8*)(&vtile[tk2][c2 * 16]) = *(const f16x8*)(qkv + srow);
      *(f16x8*)(&vtile[tk2][c2 * 16 + 8]) = *(const f16x8*)(qkv + srow + 8);
    }
    __syncthreads();
    {
      const int d = tid >> 2, seg = tid & 3;
      __align__(16) f16 tmp[16];
#pragma unroll
      for (int i = 0; i < 16; ++i) tmp[i] = vtile[seg * 16 + i][d];
      const size_t drow = (((size_t)(b * H_ + h2)) * 64 + d) * N_ + n0 + seg * 16;
      *(f16x8*)(Vt + drow) = *(const f16x8*)(tmp);
      *(f16x8*)(Vt + drow + 8) = *(const f16x8*)(tmp + 8);
    }
  }
}

// ---------------------------------------------------------------- flash attention
// grid: bh(32) * qblk(32); 4 waves, each owns 16 q rows. 64-key tiles.
__global__ __launch_bounds__(256) void attn_kernel(const f16* __restrict__ Qh,
                                                   const f16* __restrict__ Kh,
                                                   const f16* __restrict__ Vt,
                                                   f16* __restrict__ Y) {
  __shared__ __align__(16) f16 Ks[64 * 64];
  __shared__ __align__(16) f16 Vs[64 * 64];
  __shared__ __align__(16) f16 Ps[4][16 * 72];
  const int tid = threadIdx.x, lane = tid & 63, w = tid >> 6;
  const int bh = blockIdx.x >> 5;
  const int qblk = blockIdx.x & 31;
  const int b = bh >> 4, h = bh & 15;
  const f16* Qb = Qh + (size_t)bh * N_ * 64;
  const f16* Kb = Kh + (size_t)bh * N_ * 64;
  const f16* Vb = Vt + (size_t)bh * 64 * N_;
  const int cl = lane & 15, cg = lane >> 4;

  // Q fragments in registers, softmax scale (1/8, exact in f16) folded in.
  f16x8 aq[2];
  {
    const int row = qblk * 64 + w * 16 + cl;
#pragma unroll
    for (int ks = 0; ks < 2; ++ks) {
      f16x8 v = *(const f16x8*)(Qb + (size_t)row * 64 + ks * 32 + cg * 8);
#pragma unroll
      for (int j = 0; j < 8; ++j) v[j] = v[j] * (f16)0.125f;
      aq[ks] = v;
    }
  }

  f32x4 O[4];
#pragma unroll
  for (int nf = 0; nf < 4; ++nf) O[nf] = (f32x4){0.f, 0.f, 0.f, 0.f};
  float m_run[4] = {-INFINITY, -INFINITY, -INFINITY, -INFINITY};
  float l_run[4] = {0.f, 0.f, 0.f, 0.f};

  const int sR = tid >> 3, sC = tid & 7;

  for (int kv = 0; kv < N_ / 64; ++kv) {
#pragma unroll
    for (int is = 0; is < 2; ++is) {
      const int rr = is * 32 + sR;
      const int sc = sC ^ (rr & 7);
      gload_lds16(Kb + (size_t)(kv * 64 + rr) * 64 + sc * 8, Ks + is * 2048 + tid * 8);
    }
#pragma unroll
    for (int is = 0; is < 2; ++is) {
      const int rr = is * 32 + sR;  // rr = d
      const int sc = sC ^ (rr & 7);
      gload_lds16(Vb + (size_t)rr * N_ + kv * 64 + sc * 8, Vs + is * 2048 + tid * 8);
    }
    asm volatile("s_waitcnt vmcnt(0)" ::: "memory");
    __syncthreads();

    // S = Q * K^T  (16 x 64 per wave)
    f32x4 sf[4];
#pragma unroll
    for (int nf = 0; nf < 4; ++nf) sf[nf] = (f32x4){0.f, 0.f, 0.f, 0.f};
#pragma unroll
    for (int ks = 0; ks < 2; ++ks) {
      f16x8 bk[4];
#pragma unroll
      for (int nf = 0; nf < 4; ++nf) {
        const int row = nf * 16 + cl;  // key-local
        const int ck = (ks * 4 + cg) ^ (row & 7);
        bk[nf] = *(const f16x8*)(Ks + row * 64 + ck * 8);
      }
#pragma unroll
      for (int nf = 0; nf < 4; ++nf)
        sf[nf] = __builtin_amdgcn_mfma_f32_16x16x32_f16(aq[ks], bk[nf], sf[nf], 0, 0, 0);
    }

    // online softmax (rows live in 16-lane groups; reduce via shfl_xor 1..8)
    float p[4][4];
#pragma unroll
    for (int reg = 0; reg < 4; ++reg) {
      float mx = fmaxf(fmaxf(sf[0][reg], sf[1][reg]), fmaxf(sf[2][reg], sf[3][reg]));
#pragma unroll
      for (int d2 = 1; d2 < 16; d2 <<= 1) mx = fmaxf(mx, __shfl_xor(mx, d2));
      const float mn = fmaxf(m_run[reg], mx);
      const float corr = __expf(m_run[reg] - mn);
      m_run[reg] = mn;
      float s = 0.f;
#pragma unroll
      for (int nf = 0; nf < 4; ++nf) {
        p[nf][reg] = __expf(sf[nf][reg] - mn);
        s += p[nf][reg];
      }
#pragma unroll
      for (int d2 = 1; d2 < 16; d2 <<= 1) s += __shfl_xor(s, d2);
      l_run[reg] = l_run[reg] * corr + s;
#pragma unroll
      for (int nf = 0; nf < 4; ++nf) O[nf][reg] *= corr;
    }

    // P -> per-wave LDS (C layout) -> A fragments
    f16* Pw = &Ps[w][0];
#pragma unroll
    for (int nf = 0; nf < 4; ++nf)
#pragma unroll
      for (int reg = 0; reg < 4; ++reg)
        Pw[(cg * 4 + reg) * 72 + nf * 16 + cl] = (f16)p[nf][reg];

    f16x8 pa[2];
#pragma unroll
    for (int ks2 = 0; ks2 < 2; ++ks2)
      pa[ks2] = *(const f16x8*)(Pw + cl * 72 + ks2 * 32 + cg * 8);

    // O += P * V
#pragma unroll
    for (int ks2 = 0; ks2 < 2; ++ks2) {
      f16x8 bv[4];
#pragma unroll
      for (int nf = 0; nf < 4; ++nf) {
        const int row = nf * 16 + cl;  // dim
        const int ck = (ks2 * 4 + cg) ^ (row & 7);
        bv[nf] = *(const f16x8*)(Vs + row * 64 + ck * 8);
      }
#pragma unroll
      for (int nf = 0; nf < 4; ++nf)
        O[nf] = __builtin_amdgcn_mfma_f32_16x16x32_f16(pa[ks2], bv[nf], O[nf], 0, 0, 0);
    }
    __syncthreads();
  }

  // finalize: Y[b][n][h*64+dim]
#pragma unroll
  for (int reg = 0; reg < 4; ++reg) {
    const float inv = 1.0f / l_run[reg];
    const int n = qblk * 64 + w * 16 + cg * 4 + reg;
#pragma unroll
    for (int nf = 0; nf < 4; ++nf) {
      const int dim = nf * 16 + cl;
      Y[((size_t)b * N_ + n) * C_ + h * 64 + dim] = (f16)(O[nf][reg] * inv);
    }
  }
}

// ---------------------------------------------------------------- launch
extern "C" void kernel_launch(void* const* d_in, const int* in_sizes, int n_in,
                              void* d_out, int out_size, void* d_ws, size_t ws_size,
                              hipStream_t stream) {
  const float* x = (const float*)d_in[0];
  const float* px = (const float*)d_in[1];
  const float* py = (const float*)d_in[2];
  const float* psp = (const float*)d_in[3];
  const void* mask = (const void*)d_in[4];
  const float* Wqkv = (const float*)d_in[5];
  const float* bqkv = (const float*)d_in[6];
  const float* Wproj = (const float*)d_in[7];
  const float* bproj = (const float*)d_in[8];
  float* out = (float*)d_out;
  char* ws = (char*)d_ws;

  // workspace layout (bytes)
  f16* xh     = (f16*)(ws + 0);           //  8,388,608
  f16* Wqkvt  = (f16*)(ws + 8388608);     //  6,291,456
  f16* Wprojt = (f16*)(ws + 14680064);    //  2,097,152
  f16* qkvh   = (f16*)(ws + 16777216);    // 25,165,824
  f16* Qh     = (f16*)(ws + 41943040);    //  8,388,608
  f16* Kh     = (f16*)(ws + 50331648);    //  8,388,608
  f16* Vt     = (f16*)(ws + 58720256);    //  8,388,608
  f16* Yh     = (f16*)(ws + 67108864);    //  8,388,608
  int* mflag  = (int*)(ws + 75497472);    //  4

  detect_mask<<<1, 256, 0, stream>>>((const u32*)mask, mflag);
  cvt_x<<<2048, 256, 0, stream>>>(x, xh, (B_ * N_ * C_) / 8);
  transpose_cvt<<<dim3(96, 32), dim3(32, 8), 0, stream>>>(Wqkv, Wqkvt, C_, 3 * C_);
  transpose_cvt<<<dim3(32, 32), dim3(32, 8), 0, stream>>>(Wproj, Wprojt, C_, C_);
  gemm_bt<false><<<(4096 / 128) * (3072 / 128), 256, 0, stream>>>(
      xh, Wqkvt, bqkv, (void*)qkvh, 4096, 3072, 1024);
  rope_split<<<256, 256, 0, stream>>>(qkvh, px, py, psp, mask, mflag, Qh, Kh, Vt);
  attn_kernel<<<32 * 32, 256, 0, stream>>>(Qh, Kh, Vt, Yh);
  gemm_bt<true><<<(4096 / 128) * (1024 / 128), 256, 0, stream>>>(
      Yh, Wprojt, bproj, (void*)out, 4096, 1024, 1024);
}

// Round 3
// 175.186 us; speedup vs baseline: 1.2188x; 1.2188x over previous
//
#include <hip/hip_runtime.h>
#include <hip/hip_fp16.h>

typedef _Float16 f16;
typedef unsigned int u32;
typedef _Float16 f16x4 __attribute__((ext_vector_type(4)));
typedef _Float16 f16x8 __attribute__((ext_vector_type(8)));
typedef float f32x4 __attribute__((ext_vector_type(4)));
typedef float f32x16 __attribute__((ext_vector_type(16)));

#define B_  2
#define N_  2048
#define C_  1024
#define H_  16
#define HD_ 64

// ---------------------------------------------------------------- helpers
__device__ __forceinline__ void gload_lds16(const void* g, void* l) {
  __builtin_amdgcn_global_load_lds((const __attribute__((address_space(1))) u32*)g,
                                   (__attribute__((address_space(3))) u32*)l,
                                   16, 0, 0);
}

__device__ __forceinline__ u32 pack_f16(float a, float b) {
  auto h2 = __builtin_amdgcn_cvt_pkrtz(a, b);   // __fp16 ext_vector(2)
  return __builtin_bit_cast(u32, h2);
}

// ---------------------------------------------------------------- mask dtype probe
__global__ void detect_mask(const u32* __restrict__ m, int* __restrict__ flag) {
  __shared__ int bad;
  if (threadIdx.x == 0) bad = 0;
  __syncthreads();
  int v = 0;
  for (int i = threadIdx.x; i < 1024; i += 256) {
    u32 w = m[i];
    if (w != 0u && w != 1u && w != 0x3F800000u) v = 1;
  }
  if (v) atomicOr(&bad, 1);
  __syncthreads();
  if (threadIdx.x == 0) *flag = bad;   // 1 => byte mask, 0 => 4-byte mask
}

// ---------------------------------------------------------------- x f32 -> f16
__global__ __launch_bounds__(256) void cvt_x(const float* __restrict__ in,
                                             f16* __restrict__ out, int n8) {
  const int i = blockIdx.x * 256 + threadIdx.x;
  if (i >= n8) return;
  const float4 a = ((const float4*)in)[i * 2];
  const float4 b = ((const float4*)in)[i * 2 + 1];
  f16x8 o = {(f16)a.x, (f16)a.y, (f16)a.z, (f16)a.w,
             (f16)b.x, (f16)b.y, (f16)b.z, (f16)b.w};
  ((f16x8*)out)[i] = o;
}

// ---------------------------------------------------------------- W (RxC f32) -> Wt (CxR f16)
__global__ __launch_bounds__(256) void transpose_cvt(const float* __restrict__ W,
                                                     f16* __restrict__ Wt,
                                                     int R, int Ccols) {
  __shared__ __align__(16) f16 tile[32][34];
  const int c0 = blockIdx.x * 32, r0 = blockIdx.y * 32;
  const int tx = threadIdx.x, ty = threadIdx.y;  // 32 x 8
#pragma unroll
  for (int k = 0; k < 4; ++k)
    tile[ty + 8 * k][tx] = (f16)W[(size_t)(r0 + ty + 8 * k) * Ccols + c0 + tx];
  __syncthreads();
#pragma unroll
  for (int k = 0; k < 4; ++k)
    Wt[(size_t)(c0 + ty + 8 * k) * R + r0 + tx] = tile[tx][ty + 8 * k];
}

// ---------------------------------------------------------------- GEMM  C = A(MxK) * Bt(NxK)^T + bias
template <bool OUT_F32>
__global__ __launch_bounds__(256) void gemm_bt(const f16* __restrict__ A,
                                               const f16* __restrict__ Bt,
                                               const float* __restrict__ bias,
                                               void* __restrict__ Cout,
                                               int M, int N, int K) {
  __shared__ __align__(16) f16 As[128 * 64];
  __shared__ __align__(16) f16 Bs[128 * 64];
  const int tid = threadIdx.x;
  const int lane = tid & 63;
  const int wv = tid >> 6;
  const int wm = wv >> 1, wn = wv & 1;
  const int nTN = N >> 7;
  const int tM = blockIdx.x / nTN, tN = blockIdx.x % nTN;
  const int rowBase = tM << 7, colBase = tN << 7;
  const int cl = lane & 15, cg = lane >> 4;

  f32x4 acc[4][4];
#pragma unroll
  for (int i = 0; i < 4; ++i)
#pragma unroll
    for (int j = 0; j < 4; ++j) acc[i][j] = (f32x4){0.f, 0.f, 0.f, 0.f};

  const int sR = tid >> 3, sC = tid & 7;

  for (int k0 = 0; k0 < K; k0 += 64) {
#pragma unroll
    for (int is = 0; is < 4; ++is) {
      const int r = is * 32 + sR;
      const int sc = sC ^ (r & 7);
      gload_lds16(A + (size_t)(rowBase + r) * K + k0 + sc * 8, As + is * 2048 + tid * 8);
    }
#pragma unroll
    for (int is = 0; is < 4; ++is) {
      const int r = is * 32 + sR;
      const int sc = sC ^ (r & 7);
      gload_lds16(Bt + (size_t)(colBase + r) * K + k0 + sc * 8, Bs + is * 2048 + tid * 8);
    }
    asm volatile("s_waitcnt vmcnt(0)" ::: "memory");
    __syncthreads();

#pragma unroll
    for (int ks = 0; ks < 2; ++ks) {
      f16x8 af[4], bf[4];
#pragma unroll
      for (int m = 0; m < 4; ++m) {
        const int row = wm * 64 + m * 16 + cl;
        const int ck = (ks * 4 + cg) ^ (row & 7);
        af[m] = *(const f16x8*)(As + row * 64 + ck * 8);
      }
#pragma unroll
      for (int n = 0; n < 4; ++n) {
        const int row = wn * 64 + n * 16 + cl;
        const int ck = (ks * 4 + cg) ^ (row & 7);
        bf[n] = *(const f16x8*)(Bs + row * 64 + ck * 8);
      }
#pragma unroll
      for (int m = 0; m < 4; ++m)
#pragma unroll
        for (int n = 0; n < 4; ++n)
          acc[m][n] = __builtin_amdgcn_mfma_f32_16x16x32_f16(af[m], bf[n], acc[m][n], 0, 0, 0);
    }
    __syncthreads();
  }

#pragma unroll
  for (int m = 0; m < 4; ++m) {
#pragma unroll
    for (int n = 0; n < 4; ++n) {
      const int gr0 = rowBase + wm * 64 + m * 16 + cg * 4;
      const int gc = colBase + wn * 64 + n * 16 + cl;
      const float bz = bias[gc];
#pragma unroll
      for (int reg = 0; reg < 4; ++reg) {
        const float v = acc[m][n][reg] + bz;
        if (OUT_F32)
          ((float*)Cout)[(size_t)(gr0 + reg) * N + gc] = v;
        else
          ((f16*)Cout)[(size_t)(gr0 + reg) * N + gc] = (f16)v;
      }
    }
  }
}

// ---------------------------------------------------------------- RoPE + split
__global__ __launch_bounds__(256) void rope_split(const f16* __restrict__ qkv,
                                                  const float* __restrict__ px,
                                                  const float* __restrict__ py,
                                                  const float* __restrict__ psp,
                                                  const void* __restrict__ maskPtr,
                                                  const int* __restrict__ maskFlag,
                                                  f16* __restrict__ Qh,
                                                  f16* __restrict__ Kh,
                                                  f16* __restrict__ Vt) {
  __shared__ float cs[64][32], sn[64][32];
  __shared__ __align__(16) f16 vtile[64][72];
  const int tid = threadIdx.x;
  const int blk = blockIdx.x;
  const int hg = blk & 3;
  const int nt = (blk >> 2) & 31;
  const int b = blk >> 7;
  const int n0 = nt * 64;
  const int byteMode = *maskFlag;

  for (int i = tid; i < 64 * 32; i += 256) {
    const int tk = i >> 5, j = i & 31;
    const int n = n0 + tk;
    float ph;
    if (j < 12)      ph = px[((size_t)b * N_ + n) * 12 + j];
    else if (j < 24) ph = py[((size_t)b * N_ + n) * 12 + (j - 12)];
    else             ph = psp[((size_t)b * N_ + n) * 8 + (j - 24)];
    cs[tk][j] = __cosf(ph);
    sn[tk][j] = __sinf(ph);
  }
  __syncthreads();

  const int tk = tid >> 2, hl = tid & 3;
  const int h = hg * 4 + hl;
  const int n = n0 + tk;
  const size_t midx = (size_t)b * N_ + n;
  const bool doRope = byteMode ? (((const unsigned char*)maskPtr)[midx] != 0)
                               : (((const u32*)maskPtr)[midx] != 0u);
  const size_t inRow = ((size_t)b * N_ + n) * 3072 + (size_t)h * 64;
  const size_t outRow = (((size_t)(b * H_ + h)) * N_ + n) * 64;

#pragma unroll
  for (int sec = 0; sec < 2; ++sec) {
    const f16* src = qkv + inRow + sec * 1024;
    float t[64];
#pragma unroll
    for (int c = 0; c < 8; ++c) {
      f16x8 v = *(const f16x8*)(src + c * 8);
#pragma unroll
      for (int j = 0; j < 8; ++j) t[c * 8 + j] = (float)v[j];
    }
    __align__(16) f16 o[64];
    if (doRope) {
#pragma unroll
      for (int d = 0; d < 64; ++d) {
        int j;
        float rot;
        if (d < 24) {
          j = (d < 12) ? d : d - 12;
          rot = (d < 12) ? -t[d + 12] : t[d - 12];
        } else if (d < 48) {
          const int dd = d - 24;
          j = 12 + ((dd < 12) ? dd : dd - 12);
          rot = (dd < 12) ? -t[d + 12] : t[d - 12];
        } else {
          const int dd = d - 48;
          j = 24 + ((dd < 8) ? dd : dd - 8);
          rot = (dd < 8) ? -t[d + 8] : t[d - 8];
        }
        o[d] = (f16)(t[d] * cs[tk][j] + rot * sn[tk][j]);
      }
    } else {
#pragma unroll
      for (int d = 0; d < 64; ++d) o[d] = (f16)t[d];
    }
    f16* dst = (sec == 0 ? Qh : Kh) + outRow;
#pragma unroll
    for (int c = 0; c < 8; ++c) *(f16x8*)(dst + c * 8) = *(const f16x8*)(o + c * 8);
  }

  for (int hl2 = 0; hl2 < 4; ++hl2) {
    const int h2 = hg * 4 + hl2;
    __syncthreads();
    {
      const int tk2 = tid >> 2, c2 = tid & 3;
      const size_t srow = ((size_t)b * N_ + n0 + tk2) * 3072 + 2048 + (size_t)h2 * 64 + c2 * 16;
      *(f16x8*)(&vtile[tk2][c2 * 16]) = *(const f16x8*)(qkv + srow);
      *(f16x8*)(&vtile[tk2][c2 * 16 + 8]) = *(const f16x8*)(qkv + srow + 8);
    }
    __syncthreads();
    {
      const int d = tid >> 2, seg = tid & 3;
      __align__(16) f16 tmp[16];
#pragma unroll
      for (int i = 0; i < 16; ++i) tmp[i] = vtile[seg * 16 + i][d];
      const size_t drow = (((size_t)(b * H_ + h2)) * 64 + d) * N_ + n0 + seg * 16;
      *(f16x8*)(Vt + drow) = *(const f16x8*)(tmp);
      *(f16x8*)(Vt + drow + 8) = *(const f16x8*)(tmp + 8);
    }
  }
}

// ---------------------------------------------------------------- flash attention v2
// Swapped QK^T (32x32x16): S^T col=q=lane&31 -> softmax lane-local.
// O^T = V^T * P^T keeps rescale lane-local. P redistribution via
// cvt_pkrtz + v_permlane32_swap_b32. Defer-max THR=8 (log2 domain).
// 4 waves x 32 q-rows; 64-key double-buffered LDS stages.
__global__ __launch_bounds__(256) void attn2(const f16* __restrict__ Qh,
                                             const f16* __restrict__ Kh,
                                             const f16* __restrict__ Vt,
                                             f16* __restrict__ Y) {
  __shared__ __align__(16) f16 lds[2][2][4096];  // [buf][K/V][64*64]
  const int tid = threadIdx.x, lane = tid & 63, w = tid >> 6;
  int bid = blockIdx.x;
  bid = (bid & 7) * 64 + (bid >> 3);  // XCD-chunked swizzle (512 % 8 == 0)
  const int bh = bid >> 4, qb = bid & 15;
  const int b = bh >> 4, h = bh & 15;
  const f16* Qb = Qh + (size_t)bh * N_ * 64;
  const f16* Kb = Kh + (size_t)bh * N_ * 64;
  const f16* Vb = Vt + (size_t)bh * 64 * N_;
  const int ql = lane & 31, hi = lane >> 5;

  // Q as MFMA B-operand frags; fold 0.125*log2(e) (softmax in base-2)
  f16x8 qf[4];
  {
    const int qrow = qb * 128 + w * 32 + ql;
    const f16 scl = (f16)0.18033688f;
#pragma unroll
    for (int ks = 0; ks < 4; ++ks) {
      f16x8 v = *(const f16x8*)(Qb + (size_t)qrow * 64 + ks * 16 + hi * 8);
#pragma unroll
      for (int j = 0; j < 8; ++j) v[j] *= scl;
      qf[ks] = v;
    }
  }

  f32x16 Of[2];
#pragma unroll
  for (int d = 0; d < 2; ++d)
#pragma unroll
    for (int r = 0; r < 16; ++r) Of[d][r] = 0.f;
  float m_run = -1e30f, l_run = 0.f;

  const int sr = tid >> 3, sc = tid & 7;
#define STAGE(t, bb)                                                                     \
  {                                                                                      \
    _Pragma("unroll") for (int i = 0; i < 2; ++i) {                                      \
      const int row = i * 32 + sr;                                                       \
      const int g = sc ^ (row & 7);                                                      \
      gload_lds16(Kb + (size_t)((t) * 64 + row) * 64 + g * 8,                            \
                  &lds[bb][0][i * 2048 + tid * 8]);                                      \
    }                                                                                    \
    _Pragma("unroll") for (int i = 0; i < 2; ++i) {                                      \
      const int row = i * 32 + sr;                                                       \
      const int g = sc ^ (row & 7);                                                      \
      gload_lds16(Vb + (size_t)row * N_ + (t) * 64 + g * 8,                              \
                  &lds[bb][1][i * 2048 + tid * 8]);                                      \
    }                                                                                    \
  }

  STAGE(0, 0);
  asm volatile("s_waitcnt vmcnt(0)" ::: "memory");
  __syncthreads();

  int cur = 0;
  for (int t = 0; t < N_ / 64; ++t) {
    if (t < N_ / 64 - 1) STAGE(t + 1, cur ^ 1);
    const f16* Ks = &lds[cur][0][0];
    const f16* Vs = &lds[cur][1][0];
#pragma unroll
    for (int s = 0; s < 2; ++s) {
      // ---- S^T = K * Q  (32 keys x 32 q), k-dim = 64
      f32x16 sa;
#pragma unroll
      for (int r = 0; r < 16; ++r) sa[r] = 0.f;
      const int krow = s * 32 + ql;
      __builtin_amdgcn_s_setprio(1);
#pragma unroll
      for (int ks = 0; ks < 4; ++ks) {
        f16x8 kf = *(const f16x8*)(Ks + krow * 64 + ((ks * 2 + hi) ^ (krow & 7)) * 8);
        sa = __builtin_amdgcn_mfma_f32_32x32x16_f16(kf, qf[ks], sa, 0, 0, 0);
      }
      __builtin_amdgcn_s_setprio(0);

      // ---- row max (16 in-reg + 1 cross-half)
      float m0 = fmaxf(fmaxf(fmaxf(sa[0], sa[1]), fmaxf(sa[2], sa[3])),
                       fmaxf(fmaxf(sa[4], sa[5]), fmaxf(sa[6], sa[7])));
      float m1 = fmaxf(fmaxf(fmaxf(sa[8], sa[9]), fmaxf(sa[10], sa[11])),
                       fmaxf(fmaxf(sa[12], sa[13]), fmaxf(sa[14], sa[15])));
      float pmax = fmaxf(m0, m1);
      pmax = fmaxf(pmax, __shfl_xor(pmax, 32));

      // ---- defer-max rescale (T13)
      if (__any(pmax > m_run + 8.0f)) {
        const float mnew = fmaxf(m_run, pmax);
        const float corr = exp2f(m_run - mnew);
        l_run *= corr;
#pragma unroll
        for (int d = 0; d < 2; ++d)
#pragma unroll
          for (int r = 0; r < 16; ++r) Of[d][r] *= corr;
        m_run = mnew;
      }

      // ---- exp2 + row sum
#pragma unroll
      for (int r = 0; r < 16; ++r) sa[r] = exp2f(sa[r] - m_run);
      float s0 = ((sa[0] + sa[1]) + (sa[2] + sa[3])) + ((sa[4] + sa[5]) + (sa[6] + sa[7]));
      float s1 = ((sa[8] + sa[9]) + (sa[10] + sa[11])) + ((sa[12] + sa[13]) + (sa[14] + sa[15]));
      float ssum = s0 + s1;
      ssum += __shfl_xor(ssum, 32);
      l_run += ssum;

      // ---- pack P -> f16 words
      u32 pw[8];
#pragma unroll
      for (int tt = 0; tt < 8; ++tt) pw[tt] = pack_f16(sa[2 * tt], sa[2 * tt + 1]);

      // ---- PV: O^T += V^T * P^T
#pragma unroll
      for (int kk = 0; kk < 2; ++kk) {
        u32 a0 = pw[4 * kk], a1 = pw[4 * kk + 1];
        u32 b0 = pw[4 * kk + 2], b1 = pw[4 * kk + 3];
        asm volatile("v_permlane32_swap_b32 %0, %1" : "+v"(a0), "+v"(b0));
        asm volatile("v_permlane32_swap_b32 %0, %1" : "+v"(a1), "+v"(b1));
        union { u32 u[4]; f16x8 v; } pf;
        pf.u[0] = a0; pf.u[1] = a1; pf.u[2] = b0; pf.u[3] = b1;
        __builtin_amdgcn_s_setprio(1);
#pragma unroll
        for (int df = 0; df < 2; ++df) {
          const int d = df * 32 + ql;
          f16x8 vf = *(const f16x8*)(Vs + d * 64 + ((s * 4 + kk * 2 + hi) ^ (d & 7)) * 8);
          Of[df] = __builtin_amdgcn_mfma_f32_32x32x16_f16(vf, pf.v, Of[df], 0, 0, 0);
        }
        __builtin_amdgcn_s_setprio(0);
      }
    }
    asm volatile("s_waitcnt vmcnt(0)" ::: "memory");
    __syncthreads();
    cur ^= 1;
  }

  // ---- epilogue: O^T regs -> LDS transpose -> coalesced f16 stores
  const float inv = 1.0f / l_run;
  f16* Ow = &lds[0][0][0] + w * (32 * 72);
#pragma unroll
  for (int df = 0; df < 2; ++df)
#pragma unroll
    for (int g = 0; g < 4; ++g) {
      f16x4 ov;
#pragma unroll
      for (int e = 0; e < 4; ++e) ov[e] = (f16)(Of[df][g * 4 + e] * inv);
      *(f16x4*)(Ow + ql * 72 + df * 32 + g * 8 + hi * 4) = ov;
    }
  __syncthreads();
  const int rr = lane >> 1, half = lane & 1;
  const f16* srcp = Ow + rr * 72 + half * 32;
  const int nglob = qb * 128 + w * 32 + rr;
  f16* dst = Y + ((size_t)b * N_ + nglob) * C_ + h * 64 + half * 32;
#pragma unroll
  for (int c2 = 0; c2 < 4; ++c2)
    *(f16x8*)(dst + c2 * 8) = *(const f16x8*)(srcp + c2 * 8);
}

// ---------------------------------------------------------------- launch
extern "C" void kernel_launch(void* const* d_in, const int* in_sizes, int n_in,
                              void* d_out, int out_size, void* d_ws, size_t ws_size,
                              hipStream_t stream) {
  const float* x = (const float*)d_in[0];
  const float* px = (const float*)d_in[1];
  const float* py = (const float*)d_in[2];
  const float* psp = (const float*)d_in[3];
  const void* mask = (const void*)d_in[4];
  const float* Wqkv = (const float*)d_in[5];
  const float* bqkv = (const float*)d_in[6];
  const float* Wproj = (const float*)d_in[7];
  const float* bproj = (const float*)d_in[8];
  float* out = (float*)d_out;
  char* ws = (char*)d_ws;

  f16* xh     = (f16*)(ws + 0);           //  8,388,608
  f16* Wqkvt  = (f16*)(ws + 8388608);     //  6,291,456
  f16* Wprojt = (f16*)(ws + 14680064);    //  2,097,152
  f16* qkvh   = (f16*)(ws + 16777216);    // 25,165,824
  f16* Qh     = (f16*)(ws + 41943040);    //  8,388,608
  f16* Kh     = (f16*)(ws + 50331648);    //  8,388,608
  f16* Vt     = (f16*)(ws + 58720256);    //  8,388,608
  f16* Yh     = (f16*)(ws + 67108864);    //  8,388,608
  int* mflag  = (int*)(ws + 75497472);    //  4

  detect_mask<<<1, 256, 0, stream>>>((const u32*)mask, mflag);
  cvt_x<<<2048, 256, 0, stream>>>(x, xh, (B_ * N_ * C_) / 8);
  transpose_cvt<<<dim3(96, 32), dim3(32, 8), 0, stream>>>(Wqkv, Wqkvt, C_, 3 * C_);
  transpose_cvt<<<dim3(32, 32), dim3(32, 8), 0, stream>>>(Wproj, Wprojt, C_, C_);
  gemm_bt<false><<<(4096 / 128) * (3072 / 128), 256, 0, stream>>>(
      xh, Wqkvt, bqkv, (void*)qkvh, 4096, 3072, 1024);
  rope_split<<<256, 256, 0, stream>>>(qkvh, px, py, psp, mask, mflag, Qh, Kh, Vt);
  attn2<<<512, 256, 0, stream>>>(Qh, Kh, Vt, Yh);
  gemm_bt<true><<<(4096 / 128) * (1024 / 128), 256, 0, stream>>>(
      Yh, Wprojt, bproj, (void*)out, 4096, 1024, 1024);
}

// Round 8
// 172.421 us; speedup vs baseline: 1.2383x; 1.0160x over previous
//
#include <hip/hip_runtime.h>
#include <hip/hip_fp16.h>

typedef _Float16 f16;
typedef unsigned int u32;
typedef _Float16 f16x4 __attribute__((ext_vector_type(4)));
typedef _Float16 f16x8 __attribute__((ext_vector_type(8)));
typedef float f32x4 __attribute__((ext_vector_type(4)));
typedef float f32x16 __attribute__((ext_vector_type(16)));

#define B_  2
#define N_  2048
#define C_  1024
#define H_  16
#define HD_ 64

// ---------------------------------------------------------------- helpers
__device__ __forceinline__ void gload_lds16(const void* g, void* l) {
  __builtin_amdgcn_global_load_lds((const __attribute__((address_space(1))) u32*)g,
                                   (__attribute__((address_space(3))) u32*)l,
                                   16, 0, 0);
}

__device__ __forceinline__ u32 pack_f16(float a, float b) {
  auto h2 = __builtin_amdgcn_cvt_pkrtz(a, b);   // __fp16 ext_vector(2)
  return __builtin_bit_cast(u32, h2);
}

// ---------------------------------------------------------------- mask dtype probe
__global__ void detect_mask(const u32* __restrict__ m, int* __restrict__ flag) {
  __shared__ int bad;
  if (threadIdx.x == 0) bad = 0;
  __syncthreads();
  int v = 0;
  for (int i = threadIdx.x; i < 1024; i += 256) {
    u32 w = m[i];
    if (w != 0u && w != 1u && w != 0x3F800000u) v = 1;
  }
  if (v) atomicOr(&bad, 1);
  __syncthreads();
  if (threadIdx.x == 0) *flag = bad;   // 1 => byte mask, 0 => 4-byte mask
}

// ---------------------------------------------------------------- x f32 -> f16
__global__ __launch_bounds__(256) void cvt_x(const float* __restrict__ in,
                                             f16* __restrict__ out, int n8) {
  const int i = blockIdx.x * 256 + threadIdx.x;
  if (i >= n8) return;
  const float4 a = ((const float4*)in)[i * 2];
  const float4 b = ((const float4*)in)[i * 2 + 1];
  f16x8 o = {(f16)a.x, (f16)a.y, (f16)a.z, (f16)a.w,
             (f16)b.x, (f16)b.y, (f16)b.z, (f16)b.w};
  ((f16x8*)out)[i] = o;
}

// ---------------------------------------------------------------- W (RxC f32) -> Wt (CxR f16)
__global__ __launch_bounds__(256) void transpose_cvt(const float* __restrict__ W,
                                                     f16* __restrict__ Wt,
                                                     int R, int Ccols) {
  __shared__ __align__(16) f16 tile[32][34];
  const int c0 = blockIdx.x * 32, r0 = blockIdx.y * 32;
  const int tx = threadIdx.x, ty = threadIdx.y;  // 32 x 8
#pragma unroll
  for (int k = 0; k < 4; ++k)
    tile[ty + 8 * k][tx] = (f16)W[(size_t)(r0 + ty + 8 * k) * Ccols + c0 + tx];
  __syncthreads();
#pragma unroll
  for (int k = 0; k < 4; ++k)
    Wt[(size_t)(c0 + ty + 8 * k) * R + r0 + tx] = tile[tx][ty + 8 * k];
}

// ---------------------------------------------------------------- GEMM  C = A(MxK) * Bt(NxK)^T + bias
// r3 body + XCD-chunked swizzle (ONLY change vs the r3-passing kernel; bijective
// for both grids: 768 = 8*96, 256 = 8*32).
template <bool OUT_F32>
__global__ __launch_bounds__(256) void gemm_bt(const f16* __restrict__ A,
                                               const f16* __restrict__ Bt,
                                               const float* __restrict__ bias,
                                               void* __restrict__ Cout,
                                               int M, int N, int K) {
  __shared__ __align__(16) f16 As[128 * 64];
  __shared__ __align__(16) f16 Bs[128 * 64];
  const int tid = threadIdx.x;
  const int lane = tid & 63;
  const int wv = tid >> 6;
  const int wm = wv >> 1, wn = wv & 1;
  const int nTN = N >> 7;
  int bid = blockIdx.x;
  const int cpx = gridDim.x >> 3;
  bid = (bid & 7) * cpx + (bid >> 3);
  const int tM = bid / nTN, tN = bid % nTN;
  const int rowBase = tM << 7, colBase = tN << 7;
  const int cl = lane & 15, cg = lane >> 4;

  f32x4 acc[4][4];
#pragma unroll
  for (int i = 0; i < 4; ++i)
#pragma unroll
    for (int j = 0; j < 4; ++j) acc[i][j] = (f32x4){0.f, 0.f, 0.f, 0.f};

  const int sR = tid >> 3, sC = tid & 7;

  for (int k0 = 0; k0 < K; k0 += 64) {
#pragma unroll
    for (int is = 0; is < 4; ++is) {
      const int r = is * 32 + sR;
      const int sc = sC ^ (r & 7);
      gload_lds16(A + (size_t)(rowBase + r) * K + k0 + sc * 8, As + is * 2048 + tid * 8);
    }
#pragma unroll
    for (int is = 0; is < 4; ++is) {
      const int r = is * 32 + sR;
      const int sc = sC ^ (r & 7);
      gload_lds16(Bt + (size_t)(colBase + r) * K + k0 + sc * 8, Bs + is * 2048 + tid * 8);
    }
    asm volatile("s_waitcnt vmcnt(0)" ::: "memory");
    __syncthreads();

#pragma unroll
    for (int ks = 0; ks < 2; ++ks) {
      f16x8 af[4], bf[4];
#pragma unroll
      for (int m = 0; m < 4; ++m) {
        const int row = wm * 64 + m * 16 + cl;
        const int ck = (ks * 4 + cg) ^ (row & 7);
        af[m] = *(const f16x8*)(As + row * 64 + ck * 8);
      }
#pragma unroll
      for (int n = 0; n < 4; ++n) {
        const int row = wn * 64 + n * 16 + cl;
        const int ck = (ks * 4 + cg) ^ (row & 7);
        bf[n] = *(const f16x8*)(Bs + row * 64 + ck * 8);
      }
#pragma unroll
      for (int m = 0; m < 4; ++m)
#pragma unroll
        for (int n = 0; n < 4; ++n)
          acc[m][n] = __builtin_amdgcn_mfma_f32_16x16x32_f16(af[m], bf[n], acc[m][n], 0, 0, 0);
    }
    __syncthreads();
  }

#pragma unroll
  for (int m = 0; m < 4; ++m) {
#pragma unroll
    for (int n = 0; n < 4; ++n) {
      const int gr0 = rowBase + wm * 64 + m * 16 + cg * 4;
      const int gc = colBase + wn * 64 + n * 16 + cl;
      const float bz = bias[gc];
#pragma unroll
      for (int reg = 0; reg < 4; ++reg) {
        const float v = acc[m][n][reg] + bz;
        if (OUT_F32)
          ((float*)Cout)[(size_t)(gr0 + reg) * N + gc] = v;
        else
          ((f16*)Cout)[(size_t)(gr0 + reg) * N + gc] = (f16)v;
      }
    }
  }
}

// ---------------------------------------------------------------- RoPE + split (r3 verbatim)
__global__ __launch_bounds__(256) void rope_split(const f16* __restrict__ qkv,
                                                  const float* __restrict__ px,
                                                  const float* __restrict__ py,
                                                  const float* __restrict__ psp,
                                                  const void* __restrict__ maskPtr,
                                                  const int* __restrict__ maskFlag,
                                                  f16* __restrict__ Qh,
                                                  f16* __restrict__ Kh,
                                                  f16* __restrict__ Vt) {
  __shared__ float cs[64][32], sn[64][32];
  __shared__ __align__(16) f16 vtile[64][72];
  const int tid = threadIdx.x;
  const int blk = blockIdx.x;
  const int hg = blk & 3;
  const int nt = (blk >> 2) & 31;
  const int b = blk >> 7;
  const int n0 = nt * 64;
  const int byteMode = *maskFlag;

  for (int i = tid; i < 64 * 32; i += 256) {
    const int tk = i >> 5, j = i & 31;
    const int n = n0 + tk;
    float ph;
    if (j < 12)      ph = px[((size_t)b * N_ + n) * 12 + j];
    else if (j < 24) ph = py[((size_t)b * N_ + n) * 12 + (j - 12)];
    else             ph = psp[((size_t)b * N_ + n) * 8 + (j - 24)];
    cs[tk][j] = __cosf(ph);
    sn[tk][j] = __sinf(ph);
  }
  __syncthreads();

  const int tk = tid >> 2, hl = tid & 3;
  const int h = hg * 4 + hl;
  const int n = n0 + tk;
  const size_t midx = (size_t)b * N_ + n;
  const bool doRope = byteMode ? (((const unsigned char*)maskPtr)[midx] != 0)
                               : (((const u32*)maskPtr)[midx] != 0u);
  const size_t inRow = ((size_t)b * N_ + n) * 3072 + (size_t)h * 64;
  const size_t outRow = (((size_t)(b * H_ + h)) * N_ + n) * 64;

#pragma unroll
  for (int sec = 0; sec < 2; ++sec) {
    const f16* src = qkv + inRow + sec * 1024;
    float t[64];
#pragma unroll
    for (int c = 0; c < 8; ++c) {
      f16x8 v = *(const f16x8*)(src + c * 8);
#pragma unroll
      for (int j = 0; j < 8; ++j) t[c * 8 + j] = (float)v[j];
    }
    __align__(16) f16 o[64];
    if (doRope) {
#pragma unroll
      for (int d = 0; d < 64; ++d) {
        int j;
        float rot;
        if (d < 24) {
          j = (d < 12) ? d : d - 12;
          rot = (d < 12) ? -t[d + 12] : t[d - 12];
        } else if (d < 48) {
          const int dd = d - 24;
          j = 12 + ((dd < 12) ? dd : dd - 12);
          rot = (dd < 12) ? -t[d + 12] : t[d - 12];
        } else {
          const int dd = d - 48;
          j = 24 + ((dd < 8) ? dd : dd - 8);
          rot = (dd < 8) ? -t[d + 8] : t[d - 8];
        }
        o[d] = (f16)(t[d] * cs[tk][j] + rot * sn[tk][j]);
      }
    } else {
#pragma unroll
      for (int d = 0; d < 64; ++d) o[d] = (f16)t[d];
    }
    f16* dst = (sec == 0 ? Qh : Kh) + outRow;
#pragma unroll
    for (int c = 0; c < 8; ++c) *(f16x8*)(dst + c * 8) = *(const f16x8*)(o + c * 8);
  }

  for (int hl2 = 0; hl2 < 4; ++hl2) {
    const int h2 = hg * 4 + hl2;
    __syncthreads();
    {
      const int tk2 = tid >> 2, c2 = tid & 3;
      const size_t srow = ((size_t)b * N_ + n0 + tk2) * 3072 + 2048 + (size_t)h2 * 64 + c2 * 16;
      *(f16x8*)(&vtile[tk2][c2 * 16]) = *(const f16x8*)(qkv + srow);
      *(f16x8*)(&vtile[tk2][c2 * 16 + 8]) = *(const f16x8*)(qkv + srow + 8);
    }
    __syncthreads();
    {
      const int d = tid >> 2, seg = tid & 3;
      __align__(16) f16 tmp[16];
#pragma unroll
      for (int i = 0; i < 16; ++i) tmp[i] = vtile[seg * 16 + i][d];
      const size_t drow = (((size_t)(b * H_ + h2)) * 64 + d) * N_ + n0 + seg * 16;
      *(f16x8*)(Vt + drow) = *(const f16x8*)(tmp);
      *(f16x8*)(Vt + drow + 8) = *(const f16x8*)(tmp + 8);
    }
  }
}

// ---------------------------------------------------------------- flash attention v2 (r3 VERBATIM)
__global__ __launch_bounds__(256) void attn2(const f16* __restrict__ Qh,
                                             const f16* __restrict__ Kh,
                                             const f16* __restrict__ Vt,
                                             f16* __restrict__ Y) {
  __shared__ __align__(16) f16 lds[2][2][4096];  // [buf][K/V][64*64]
  const int tid = threadIdx.x, lane = tid & 63, w = tid >> 6;
  int bid = blockIdx.x;
  bid = (bid & 7) * 64 + (bid >> 3);  // XCD-chunked swizzle (512 % 8 == 0)
  const int bh = bid >> 4, qb = bid & 15;
  const int b = bh >> 4, h = bh & 15;
  const f16* Qb = Qh + (size_t)bh * N_ * 64;
  const f16* Kb = Kh + (size_t)bh * N_ * 64;
  const f16* Vb = Vt + (size_t)bh * 64 * N_;
  const int ql = lane & 31, hi = lane >> 5;

  // Q as MFMA B-operand frags; fold 0.125*log2(e) (softmax in base-2)
  f16x8 qf[4];
  {
    const int qrow = qb * 128 + w * 32 + ql;
    const f16 scl = (f16)0.18033688f;
#pragma unroll
    for (int ks = 0; ks < 4; ++ks) {
      f16x8 v = *(const f16x8*)(Qb + (size_t)qrow * 64 + ks * 16 + hi * 8);
#pragma unroll
      for (int j = 0; j < 8; ++j) v[j] *= scl;
      qf[ks] = v;
    }
  }

  f32x16 Of[2];
#pragma unroll
  for (int d = 0; d < 2; ++d)
#pragma unroll
    for (int r = 0; r < 16; ++r) Of[d][r] = 0.f;
  float m_run = -1e30f, l_run = 0.f;

  const int sr = tid >> 3, sc = tid & 7;
#define STAGE(t, bb)                                                                     \
  {                                                                                      \
    _Pragma("unroll") for (int i = 0; i < 2; ++i) {                                      \
      const int row = i * 32 + sr;                                                       \
      const int g = sc ^ (row & 7);                                                      \
      gload_lds16(Kb + (size_t)((t) * 64 + row) * 64 + g * 8,                            \
                  &lds[bb][0][i * 2048 + tid * 8]);                                      \
    }                                                                                    \
    _Pragma("unroll") for (int i = 0; i < 2; ++i) {                                      \
      const int row = i * 32 + sr;                                                       \
      const int g = sc ^ (row & 7);                                                      \
      gload_lds16(Vb + (size_t)row * N_ + (t) * 64 + g * 8,                              \
                  &lds[bb][1][i * 2048 + tid * 8]);                                      \
    }                                                                                    \
  }

  STAGE(0, 0);
  asm volatile("s_waitcnt vmcnt(0)" ::: "memory");
  __syncthreads();

  int cur = 0;
  for (int t = 0; t < N_ / 64; ++t) {
    if (t < N_ / 64 - 1) STAGE(t + 1, cur ^ 1);
    const f16* Ks = &lds[cur][0][0];
    const f16* Vs = &lds[cur][1][0];
#pragma unroll
    for (int s = 0; s < 2; ++s) {
      // ---- S^T = K * Q  (32 keys x 32 q), k-dim = 64
      f32x16 sa;
#pragma unroll
      for (int r = 0; r < 16; ++r) sa[r] = 0.f;
      const int krow = s * 32 + ql;
      __builtin_amdgcn_s_setprio(1);
#pragma unroll
      for (int ks = 0; ks < 4; ++ks) {
        f16x8 kf = *(const f16x8*)(Ks + krow * 64 + ((ks * 2 + hi) ^ (krow & 7)) * 8);
        sa = __builtin_amdgcn_mfma_f32_32x32x16_f16(kf, qf[ks], sa, 0, 0, 0);
      }
      __builtin_amdgcn_s_setprio(0);

      // ---- row max (16 in-reg + 1 cross-half)
      float m0 = fmaxf(fmaxf(fmaxf(sa[0], sa[1]), fmaxf(sa[2], sa[3])),
                       fmaxf(fmaxf(sa[4], sa[5]), fmaxf(sa[6], sa[7])));
      float m1 = fmaxf(fmaxf(fmaxf(sa[8], sa[9]), fmaxf(sa[10], sa[11])),
                       fmaxf(fmaxf(sa[12], sa[13]), fmaxf(sa[14], sa[15])));
      float pmax = fmaxf(m0, m1);
      pmax = fmaxf(pmax, __shfl_xor(pmax, 32));

      // ---- defer-max rescale (T13)
      if (__any(pmax > m_run + 8.0f)) {
        const float mnew = fmaxf(m_run, pmax);
        const float corr = exp2f(m_run - mnew);
        l_run *= corr;
#pragma unroll
        for (int d = 0; d < 2; ++d)
#pragma unroll
          for (int r = 0; r < 16; ++r) Of[d][r] *= corr;
        m_run = mnew;
      }

      // ---- exp2 + row sum
#pragma unroll
      for (int r = 0; r < 16; ++r) sa[r] = exp2f(sa[r] - m_run);
      float s0 = ((sa[0] + sa[1]) + (sa[2] + sa[3])) + ((sa[4] + sa[5]) + (sa[6] + sa[7]));
      float s1 = ((sa[8] + sa[9]) + (sa[10] + sa[11])) + ((sa[12] + sa[13]) + (sa[14] + sa[15]));
      float ssum = s0 + s1;
      ssum += __shfl_xor(ssum, 32);
      l_run += ssum;

      // ---- pack P -> f16 words
      u32 pw[8];
#pragma unroll
      for (int tt = 0; tt < 8; ++tt) pw[tt] = pack_f16(sa[2 * tt], sa[2 * tt + 1]);

      // ---- PV: O^T += V^T * P^T
#pragma unroll
      for (int kk = 0; kk < 2; ++kk) {
        u32 a0 = pw[4 * kk], a1 = pw[4 * kk + 1];
        u32 b0 = pw[4 * kk + 2], b1 = pw[4 * kk + 3];
        asm volatile("v_permlane32_swap_b32 %0, %1" : "+v"(a0), "+v"(b0));
        asm volatile("v_permlane32_swap_b32 %0, %1" : "+v"(a1), "+v"(b1));
        union { u32 u[4]; f16x8 v; } pf;
        pf.u[0] = a0; pf.u[1] = a1; pf.u[2] = b0; pf.u[3] = b1;
        __builtin_amdgcn_s_setprio(1);
#pragma unroll
        for (int df = 0; df < 2; ++df) {
          const int d = df * 32 + ql;
          f16x8 vf = *(const f16x8*)(Vs + d * 64 + ((s * 4 + kk * 2 + hi) ^ (d & 7)) * 8);
          Of[df] = __builtin_amdgcn_mfma_f32_32x32x16_f16(vf, pf.v, Of[df], 0, 0, 0);
        }
        __builtin_amdgcn_s_setprio(0);
      }
    }
    asm volatile("s_waitcnt vmcnt(0)" ::: "memory");
    __syncthreads();
    cur ^= 1;
  }

  // ---- epilogue: O^T regs -> LDS transpose -> coalesced f16 stores
  const float inv = 1.0f / l_run;
  f16* Ow = &lds[0][0][0] + w * (32 * 72);
#pragma unroll
  for (int df = 0; df < 2; ++df)
#pragma unroll
    for (int g = 0; g < 4; ++g) {
      f16x4 ov;
#pragma unroll
      for (int e = 0; e < 4; ++e) ov[e] = (f16)(Of[df][g * 4 + e] * inv);
      *(f16x4*)(Ow + ql * 72 + df * 32 + g * 8 + hi * 4) = ov;
    }
  __syncthreads();
  const int rr = lane >> 1, half = lane & 1;
  const f16* srcp = Ow + rr * 72 + half * 32;
  const int nglob = qb * 128 + w * 32 + rr;
  f16* dst = Y + ((size_t)b * N_ + nglob) * C_ + h * 64 + half * 32;
#pragma unroll
  for (int c2 = 0; c2 < 4; ++c2)
    *(f16x8*)(dst + c2 * 8) = *(const f16x8*)(srcp + c2 * 8);
}

// ---------------------------------------------------------------- launch
extern "C" void kernel_launch(void* const* d_in, const int* in_sizes, int n_in,
                              void* d_out, int out_size, void* d_ws, size_t ws_size,
                              hipStream_t stream) {
  const float* x = (const float*)d_in[0];
  const float* px = (const float*)d_in[1];
  const float* py = (const float*)d_in[2];
  const float* psp = (const float*)d_in[3];
  const void* mask = (const void*)d_in[4];
  const float* Wqkv = (const float*)d_in[5];
  const float* bqkv = (const float*)d_in[6];
  const float* Wproj = (const float*)d_in[7];
  const float* bproj = (const float*)d_in[8];
  float* out = (float*)d_out;
  char* ws = (char*)d_ws;

  f16* xh     = (f16*)(ws + 0);           //  8,388,608
  f16* Wqkvt  = (f16*)(ws + 8388608);     //  6,291,456
  f16* Wprojt = (f16*)(ws + 14680064);    //  2,097,152
  f16* qkvh   = (f16*)(ws + 16777216);    // 25,165,824
  f16* Qh     = (f16*)(ws + 41943040);    //  8,388,608
  f16* Kh     = (f16*)(ws + 50331648);    //  8,388,608
  f16* Vt     = (f16*)(ws + 58720256);    //  8,388,608
  f16* Yh     = (f16*)(ws + 67108864);    //  8,388,608
  int* mflag  = (int*)(ws + 75497472);    //  4

  detect_mask<<<1, 256, 0, stream>>>((const u32*)mask, mflag);
  cvt_x<<<2048, 256, 0, stream>>>(x, xh, (B_ * N_ * C_) / 8);
  transpose_cvt<<<dim3(96, 32), dim3(32, 8), 0, stream>>>(Wqkv, Wqkvt, C_, 3 * C_);
  transpose_cvt<<<dim3(32, 32), dim3(32, 8), 0, stream>>>(Wproj, Wprojt, C_, C_);
  gemm_bt<false><<<(4096 / 128) * (3072 / 128), 256, 0, stream>>>(
      xh, Wqkvt, bqkv, (void*)qkvh, 4096, 3072, 1024);
  rope_split<<<256, 256, 0, stream>>>(qkvh, px, py, psp, mask, mflag, Qh, Kh, Vt);
  attn2<<<512, 256, 0, stream>>>(Qh, Kh, Vt, Yh);
  gemm_bt<true><<<(4096 / 128) * (1024 / 128), 256, 0, stream>>>(
      Yh, Wprojt, bproj, (void*)out, 4096, 1024, 1024);
}

// Round 9
// 161.445 us; speedup vs baseline: 1.3225x; 1.0680x over previous
//
#include <hip/hip_runtime.h>
#include <hip/hip_fp16.h>

typedef _Float16 f16;
typedef unsigned int u32;
typedef _Float16 f16x4 __attribute__((ext_vector_type(4)));
typedef _Float16 f16x8 __attribute__((ext_vector_type(8)));
typedef float f32x4 __attribute__((ext_vector_type(4)));
typedef float f32x16 __attribute__((ext_vector_type(16)));

#define B_  2
#define N_  2048
#define C_  1024
#define H_  16
#define HD_ 64

// ---------------------------------------------------------------- helpers
__device__ __forceinline__ void gload_lds16(const void* g, void* l) {
  __builtin_amdgcn_global_load_lds((const __attribute__((address_space(1))) u32*)g,
                                   (__attribute__((address_space(3))) u32*)l,
                                   16, 0, 0);
}

__device__ __forceinline__ u32 pack_f16(float a, float b) {
  auto h2 = __builtin_amdgcn_cvt_pkrtz(a, b);   // __fp16 ext_vector(2)
  return __builtin_bit_cast(u32, h2);
}

// ---------------------------------------------------------------- mask dtype probe
__global__ void detect_mask(const u32* __restrict__ m, int* __restrict__ flag) {
  __shared__ int bad;
  if (threadIdx.x == 0) bad = 0;
  __syncthreads();
  int v = 0;
  for (int i = threadIdx.x; i < 1024; i += 256) {
    u32 w = m[i];
    if (w != 0u && w != 1u && w != 0x3F800000u) v = 1;
  }
  if (v) atomicOr(&bad, 1);
  __syncthreads();
  if (threadIdx.x == 0) *flag = bad;   // 1 => byte mask, 0 => 4-byte mask
}

// ---------------------------------------------------------------- x f32 -> f16
__global__ __launch_bounds__(256) void cvt_x(const float* __restrict__ in,
                                             f16* __restrict__ out, int n8) {
  const int i = blockIdx.x * 256 + threadIdx.x;
  if (i >= n8) return;
  const float4 a = ((const float4*)in)[i * 2];
  const float4 b = ((const float4*)in)[i * 2 + 1];
  f16x8 o = {(f16)a.x, (f16)a.y, (f16)a.z, (f16)a.w,
             (f16)b.x, (f16)b.y, (f16)b.z, (f16)b.w};
  ((f16x8*)out)[i] = o;
}

// ---------------------------------------------------------------- W (RxC f32) -> Wt (CxR f16)
__global__ __launch_bounds__(256) void transpose_cvt(const float* __restrict__ W,
                                                     f16* __restrict__ Wt,
                                                     int R, int Ccols) {
  __shared__ __align__(16) f16 tile[32][34];
  const int c0 = blockIdx.x * 32, r0 = blockIdx.y * 32;
  const int tx = threadIdx.x, ty = threadIdx.y;  // 32 x 8
#pragma unroll
  for (int k = 0; k < 4; ++k)
    tile[ty + 8 * k][tx] = (f16)W[(size_t)(r0 + ty + 8 * k) * Ccols + c0 + tx];
  __syncthreads();
#pragma unroll
  for (int k = 0; k < 4; ++k)
    Wt[(size_t)(c0 + ty + 8 * k) * R + r0 + tx] = tile[tx][ty + 8 * k];
}

// ---------------------------------------------------------------- GEMM  C = A(MxK) * Bt(NxK)^T + bias
template <bool OUT_F32>
__global__ __launch_bounds__(256) void gemm_bt(const f16* __restrict__ A,
                                               const f16* __restrict__ Bt,
                                               const float* __restrict__ bias,
                                               void* __restrict__ Cout,
                                               int M, int N, int K) {
  __shared__ __align__(16) f16 As[128 * 64];
  __shared__ __align__(16) f16 Bs[128 * 64];
  const int tid = threadIdx.x;
  const int lane = tid & 63;
  const int wv = tid >> 6;
  const int wm = wv >> 1, wn = wv & 1;
  const int nTN = N >> 7;
  int bid = blockIdx.x;
  const int cpx = gridDim.x >> 3;
  bid = (bid & 7) * cpx + (bid >> 3);
  const int tM = bid / nTN, tN = bid % nTN;
  const int rowBase = tM << 7, colBase = tN << 7;
  const int cl = lane & 15, cg = lane >> 4;

  f32x4 acc[4][4];
#pragma unroll
  for (int i = 0; i < 4; ++i)
#pragma unroll
    for (int j = 0; j < 4; ++j) acc[i][j] = (f32x4){0.f, 0.f, 0.f, 0.f};

  const int sR = tid >> 3, sC = tid & 7;

  for (int k0 = 0; k0 < K; k0 += 64) {
#pragma unroll
    for (int is = 0; is < 4; ++is) {
      const int r = is * 32 + sR;
      const int sc = sC ^ (r & 7);
      gload_lds16(A + (size_t)(rowBase + r) * K + k0 + sc * 8, As + is * 2048 + tid * 8);
    }
#pragma unroll
    for (int is = 0; is < 4; ++is) {
      const int r = is * 32 + sR;
      const int sc = sC ^ (r & 7);
      gload_lds16(Bt + (size_t)(colBase + r) * K + k0 + sc * 8, Bs + is * 2048 + tid * 8);
    }
    asm volatile("s_waitcnt vmcnt(0)" ::: "memory");
    __syncthreads();

#pragma unroll
    for (int ks = 0; ks < 2; ++ks) {
      f16x8 af[4], bf[4];
#pragma unroll
      for (int m = 0; m < 4; ++m) {
        const int row = wm * 64 + m * 16 + cl;
        const int ck = (ks * 4 + cg) ^ (row & 7);
        af[m] = *(const f16x8*)(As + row * 64 + ck * 8);
      }
#pragma unroll
      for (int n = 0; n < 4; ++n) {
        const int row = wn * 64 + n * 16 + cl;
        const int ck = (ks * 4 + cg) ^ (row & 7);
        bf[n] = *(const f16x8*)(Bs + row * 64 + ck * 8);
      }
#pragma unroll
      for (int m = 0; m < 4; ++m)
#pragma unroll
        for (int n = 0; n < 4; ++n)
          acc[m][n] = __builtin_amdgcn_mfma_f32_16x16x32_f16(af[m], bf[n], acc[m][n], 0, 0, 0);
    }
    __syncthreads();
  }

#pragma unroll
  for (int m = 0; m < 4; ++m) {
#pragma unroll
    for (int n = 0; n < 4; ++n) {
      const int gr0 = rowBase + wm * 64 + m * 16 + cg * 4;
      const int gc = colBase + wn * 64 + n * 16 + cl;
      const float bz = bias[gc];
#pragma unroll
      for (int reg = 0; reg < 4; ++reg) {
        const float v = acc[m][n][reg] + bz;
        if (OUT_F32)
          ((float*)Cout)[(size_t)(gr0 + reg) * N + gc] = v;
        else
          ((f16*)Cout)[(size_t)(gr0 + reg) * N + gc] = (f16)v;
      }
    }
  }
}

// ---------------------------------------------------------------- RoPE + split
__global__ __launch_bounds__(256) void rope_split(const f16* __restrict__ qkv,
                                                  const float* __restrict__ px,
                                                  const float* __restrict__ py,
                                                  const float* __restrict__ psp,
                                                  const void* __restrict__ maskPtr,
                                                  const int* __restrict__ maskFlag,
                                                  f16* __restrict__ Qh,
                                                  f16* __restrict__ Kh,
                                                  f16* __restrict__ Vt) {
  __shared__ float cs[64][32], sn[64][32];
  __shared__ __align__(16) f16 vtile[64][72];
  const int tid = threadIdx.x;
  const int blk = blockIdx.x;
  const int hg = blk & 3;
  const int nt = (blk >> 2) & 31;
  const int b = blk >> 7;
  const int n0 = nt * 64;
  const int byteMode = *maskFlag;

  for (int i = tid; i < 64 * 32; i += 256) {
    const int tk = i >> 5, j = i & 31;
    const int n = n0 + tk;
    float ph;
    if (j < 12)      ph = px[((size_t)b * N_ + n) * 12 + j];
    else if (j < 24) ph = py[((size_t)b * N_ + n) * 12 + (j - 12)];
    else             ph = psp[((size_t)b * N_ + n) * 8 + (j - 24)];
    cs[tk][j] = __cosf(ph);
    sn[tk][j] = __sinf(ph);
  }
  __syncthreads();

  const int tk = tid >> 2, hl = tid & 3;
  const int h = hg * 4 + hl;
  const int n = n0 + tk;
  const size_t midx = (size_t)b * N_ + n;
  const bool doRope = byteMode ? (((const unsigned char*)maskPtr)[midx] != 0)
                               : (((const u32*)maskPtr)[midx] != 0u);
  const size_t inRow = ((size_t)b * N_ + n) * 3072 + (size_t)h * 64;
  const size_t outRow = (((size_t)(b * H_ + h)) * N_ + n) * 64;

#pragma unroll
  for (int sec = 0; sec < 2; ++sec) {
    const f16* src = qkv + inRow + sec * 1024;
    float t[64];
#pragma unroll
    for (int c = 0; c < 8; ++c) {
      f16x8 v = *(const f16x8*)(src + c * 8);
#pragma unroll
      for (int j = 0; j < 8; ++j) t[c * 8 + j] = (float)v[j];
    }
    __align__(16) f16 o[64];
    if (doRope) {
#pragma unroll
      for (int d = 0; d < 64; ++d) {
        int j;
        float rot;
        if (d < 24) {
          j = (d < 12) ? d : d - 12;
          rot = (d < 12) ? -t[d + 12] : t[d - 12];
        } else if (d < 48) {
          const int dd = d - 24;
          j = 12 + ((dd < 12) ? dd : dd - 12);
          rot = (dd < 12) ? -t[d + 12] : t[d - 12];
        } else {
          const int dd = d - 48;
          j = 24 + ((dd < 8) ? dd : dd - 8);
          rot = (dd < 8) ? -t[d + 8] : t[d - 8];
        }
        o[d] = (f16)(t[d] * cs[tk][j] + rot * sn[tk][j]);
      }
    } else {
#pragma unroll
      for (int d = 0; d < 64; ++d) o[d] = (f16)t[d];
    }
    f16* dst = (sec == 0 ? Qh : Kh) + outRow;
#pragma unroll
    for (int c = 0; c < 8; ++c) *(f16x8*)(dst + c * 8) = *(const f16x8*)(o + c * 8);
  }

  for (int hl2 = 0; hl2 < 4; ++hl2) {
    const int h2 = hg * 4 + hl2;
    __syncthreads();
    {
      const int tk2 = tid >> 2, c2 = tid & 3;
      const size_t srow = ((size_t)b * N_ + n0 + tk2) * 3072 + 2048 + (size_t)h2 * 64 + c2 * 16;
      *(f16x8*)(&vtile[tk2][c2 * 16]) = *(const f16x8*)(qkv + srow);
      *(f16x8*)(&vtile[tk2][c2 * 16 + 8]) = *(const f16x8*)(qkv + srow + 8);
    }
    __syncthreads();
    {
      const int d = tid >> 2, seg = tid & 3;
      __align__(16) f16 tmp[16];
#pragma unroll
      for (int i = 0; i < 16; ++i) tmp[i] = vtile[seg * 16 + i][d];
      const size_t drow = (((size_t)(b * H_ + h2)) * 64 + d) * N_ + n0 + seg * 16;
      *(f16x8*)(Vt + drow) = *(const f16x8*)(tmp);
      *(f16x8*)(Vt + drow + 8) = *(const f16x8*)(tmp + 8);
    }
  }
}

// ---------------------------------------------------------------- flash attention v2
// r8 structure; softmax in natural-e domain with __expf (r1-PROVEN fast exp:
// lowers to v_mul+v_exp_f32). __builtin_amdgcn_exp2f is BANNED — every failing
// round (r4-r7) used it; r1/r3/r8 passing rounds used __expf / OCML.
__global__ __launch_bounds__(256) void attn2(const f16* __restrict__ Qh,
                                             const f16* __restrict__ Kh,
                                             const f16* __restrict__ Vt,
                                             f16* __restrict__ Y) {
  __shared__ __align__(16) f16 lds[2][2][4096];  // [buf][K/V][64*64]
  const int tid = threadIdx.x, lane = tid & 63, w = tid >> 6;
  int bid = blockIdx.x;
  bid = (bid & 7) * 64 + (bid >> 3);  // XCD-chunked swizzle (512 % 8 == 0)
  const int bh = bid >> 4, qb = bid & 15;
  const int b = bh >> 4, h = bh & 15;
  const f16* Qb = Qh + (size_t)bh * N_ * 64;
  const f16* Kb = Kh + (size_t)bh * N_ * 64;
  const f16* Vb = Vt + (size_t)bh * 64 * N_;
  const int ql = lane & 31, hi = lane >> 5;

  // Q as MFMA B-operand frags; softmax scale 1/8 (exact in f16) folded in
  f16x8 qf[4];
  {
    const int qrow = qb * 128 + w * 32 + ql;
    const f16 scl = (f16)0.125f;
#pragma unroll
    for (int ks = 0; ks < 4; ++ks) {
      f16x8 v = *(const f16x8*)(Qb + (size_t)qrow * 64 + ks * 16 + hi * 8);
#pragma unroll
      for (int j = 0; j < 8; ++j) v[j] *= scl;
      qf[ks] = v;
    }
  }

  f32x16 Of[2];
#pragma unroll
  for (int d = 0; d < 2; ++d)
#pragma unroll
    for (int r = 0; r < 16; ++r) Of[d][r] = 0.f;
  float m_run = -1e30f, l_run = 0.f;

  const int sr = tid >> 3, sc = tid & 7;
#define STAGE(t, bb)                                                                     \
  {                                                                                      \
    _Pragma("unroll") for (int i = 0; i < 2; ++i) {                                      \
      const int row = i * 32 + sr;                                                       \
      const int g = sc ^ (row & 7);                                                      \
      gload_lds16(Kb + (size_t)((t) * 64 + row) * 64 + g * 8,                            \
                  &lds[bb][0][i * 2048 + tid * 8]);                                      \
    }                                                                                    \
    _Pragma("unroll") for (int i = 0; i < 2; ++i) {                                      \
      const int row = i * 32 + sr;                                                       \
      const int g = sc ^ (row & 7);                                                      \
      gload_lds16(Vb + (size_t)row * N_ + (t) * 64 + g * 8,                              \
                  &lds[bb][1][i * 2048 + tid * 8]);                                      \
    }                                                                                    \
  }

  STAGE(0, 0);
  asm volatile("s_waitcnt vmcnt(0)" ::: "memory");
  __syncthreads();

  int cur = 0;
  for (int t = 0; t < N_ / 64; ++t) {
    if (t < N_ / 64 - 1) STAGE(t + 1, cur ^ 1);
    const f16* Ks = &lds[cur][0][0];
    const f16* Vs = &lds[cur][1][0];
#pragma unroll
    for (int s = 0; s < 2; ++s) {
      // ---- S^T = K * Q  (32 keys x 32 q), k-dim = 64
      f32x16 sa;
#pragma unroll
      for (int r = 0; r < 16; ++r) sa[r] = 0.f;
      const int krow = s * 32 + ql;
      __builtin_amdgcn_s_setprio(1);
#pragma unroll
      for (int ks = 0; ks < 4; ++ks) {
        f16x8 kf = *(const f16x8*)(Ks + krow * 64 + ((ks * 2 + hi) ^ (krow & 7)) * 8);
        sa = __builtin_amdgcn_mfma_f32_32x32x16_f16(kf, qf[ks], sa, 0, 0, 0);
      }
      __builtin_amdgcn_s_setprio(0);

      // ---- row max (in-reg + 1 cross-half shfl)
      float m0 = fmaxf(fmaxf(fmaxf(sa[0], sa[1]), fmaxf(sa[2], sa[3])),
                       fmaxf(fmaxf(sa[4], sa[5]), fmaxf(sa[6], sa[7])));
      float m1 = fmaxf(fmaxf(fmaxf(sa[8], sa[9]), fmaxf(sa[10], sa[11])),
                       fmaxf(fmaxf(sa[12], sa[13]), fmaxf(sa[14], sa[15])));
      float pmax = fmaxf(m0, m1);
      pmax = fmaxf(pmax, __shfl_xor(pmax, 32));

      // ---- defer-max rescale (T13), e-domain (P bounded by e^8)
      if (__any(pmax > m_run + 8.0f)) {
        const float mnew = fmaxf(m_run, pmax);
        const float corr = __expf(m_run - mnew);
        l_run *= corr;
#pragma unroll
        for (int d = 0; d < 2; ++d)
#pragma unroll
          for (int r = 0; r < 16; ++r) Of[d][r] *= corr;
        m_run = mnew;
      }

      // ---- exp (__expf -> v_mul+v_exp_f32) + row sum
#pragma unroll
      for (int r = 0; r < 16; ++r) sa[r] = __expf(sa[r] - m_run);
      float s0 = ((sa[0] + sa[1]) + (sa[2] + sa[3])) + ((sa[4] + sa[5]) + (sa[6] + sa[7]));
      float s1 = ((sa[8] + sa[9]) + (sa[10] + sa[11])) + ((sa[12] + sa[13]) + (sa[14] + sa[15]));
      float ssum = s0 + s1;
      ssum += __shfl_xor(ssum, 32);
      l_run += ssum;

      // ---- pack P -> f16 words
      u32 pw[8];
#pragma unroll
      for (int tt = 0; tt < 8; ++tt) pw[tt] = pack_f16(sa[2 * tt], sa[2 * tt + 1]);

      // ---- PV: O^T += V^T * P^T
#pragma unroll
      for (int kk = 0; kk < 2; ++kk) {
        u32 a0 = pw[4 * kk], a1 = pw[4 * kk + 1];
        u32 b0 = pw[4 * kk + 2], b1 = pw[4 * kk + 3];
        asm volatile("v_permlane32_swap_b32 %0, %1" : "+v"(a0), "+v"(b0));
        asm volatile("v_permlane32_swap_b32 %0, %1" : "+v"(a1), "+v"(b1));
        union { u32 u[4]; f16x8 v; } pf;
        pf.u[0] = a0; pf.u[1] = a1; pf.u[2] = b0; pf.u[3] = b1;
        __builtin_amdgcn_s_setprio(1);
#pragma unroll
        for (int df = 0; df < 2; ++df) {
          const int d = df * 32 + ql;
          f16x8 vf = *(const f16x8*)(Vs + d * 64 + ((s * 4 + kk * 2 + hi) ^ (d & 7)) * 8);
          Of[df] = __builtin_amdgcn_mfma_f32_32x32x16_f16(vf, pf.v, Of[df], 0, 0, 0);
        }
        __builtin_amdgcn_s_setprio(0);
      }
    }
    asm volatile("s_waitcnt vmcnt(0)" ::: "memory");
    __syncthreads();
    cur ^= 1;
  }

  // ---- epilogue: O^T regs -> LDS transpose -> coalesced f16 stores
  const float inv = 1.0f / l_run;
  f16* Ow = &lds[0][0][0] + w * (32 * 72);
#pragma unroll
  for (int df = 0; df < 2; ++df)
#pragma unroll
    for (int g = 0; g < 4; ++g) {
      f16x4 ov;
#pragma unroll
      for (int e = 0; e < 4; ++e) ov[e] = (f16)(Of[df][g * 4 + e] * inv);
      *(f16x4*)(Ow + ql * 72 + df * 32 + g * 8 + hi * 4) = ov;
    }
  __syncthreads();
  const int rr = lane >> 1, half = lane & 1;
  const f16* srcp = Ow + rr * 72 + half * 32;
  const int nglob = qb * 128 + w * 32 + rr;
  f16* dst = Y + ((size_t)b * N_ + nglob) * C_ + h * 64 + half * 32;
#pragma unroll
  for (int c2 = 0; c2 < 4; ++c2)
    *(f16x8*)(dst + c2 * 8) = *(const f16x8*)(srcp + c2 * 8);
}

// ---------------------------------------------------------------- launch
extern "C" void kernel_launch(void* const* d_in, const int* in_sizes, int n_in,
                              void* d_out, int out_size, void* d_ws, size_t ws_size,
                              hipStream_t stream) {
  const float* x = (const float*)d_in[0];
  const float* px = (const float*)d_in[1];
  const float* py = (const float*)d_in[2];
  const float* psp = (const float*)d_in[3];
  const void* mask = (const void*)d_in[4];
  const float* Wqkv = (const float*)d_in[5];
  const float* bqkv = (const float*)d_in[6];
  const float* Wproj = (const float*)d_in[7];
  const float* bproj = (const float*)d_in[8];
  float* out = (float*)d_out;
  char* ws = (char*)d_ws;

  f16* xh     = (f16*)(ws + 0);           //  8,388,608
  f16* Wqkvt  = (f16*)(ws + 8388608);     //  6,291,456
  f16* Wprojt = (f16*)(ws + 14680064);    //  2,097,152
  f16* qkvh   = (f16*)(ws + 16777216);    // 25,165,824
  f16* Qh     = (f16*)(ws + 41943040);    //  8,388,608
  f16* Kh     = (f16*)(ws + 50331648);    //  8,388,608
  f16* Vt     = (f16*)(ws + 58720256);    //  8,388,608
  f16* Yh     = (f16*)(ws + 67108864);    //  8,388,608
  int* mflag  = (int*)(ws + 75497472);    //  4

  detect_mask<<<1, 256, 0, stream>>>((const u32*)mask, mflag);
  cvt_x<<<2048, 256, 0, stream>>>(x, xh, (B_ * N_ * C_) / 8);
  transpose_cvt<<<dim3(96, 32), dim3(32, 8), 0, stream>>>(Wqkv, Wqkvt, C_, 3 * C_);
  transpose_cvt<<<dim3(32, 32), dim3(32, 8), 0, stream>>>(Wproj, Wprojt, C_, C_);
  gemm_bt<false><<<(4096 / 128) * (3072 / 128), 256, 0, stream>>>(
      xh, Wqkvt, bqkv, (void*)qkvh, 4096, 3072, 1024);
  rope_split<<<256, 256, 0, stream>>>(qkvh, px, py, psp, mask, mflag, Qh, Kh, Vt);
  attn2<<<512, 256, 0, stream>>>(Qh, Kh, Vt, Yh);
  gemm_bt<true><<<(4096 / 128) * (1024 / 128), 256, 0, stream>>>(
      Yh, Wprojt, bproj, (void*)out, 4096, 1024, 1024);
}

// Round 10
// 161.307 us; speedup vs baseline: 1.3236x; 1.0009x over previous
//
#include <hip/hip_runtime.h>
#include <hip/hip_fp16.h>

typedef _Float16 f16;
typedef unsigned int u32;
typedef _Float16 f16x4 __attribute__((ext_vector_type(4)));
typedef _Float16 f16x8 __attribute__((ext_vector_type(8)));
typedef float f32x4 __attribute__((ext_vector_type(4)));
typedef float f32x16 __attribute__((ext_vector_type(16)));

#define B_  2
#define N_  2048
#define C_  1024
#define H_  16
#define HD_ 64

// ---------------------------------------------------------------- helpers
__device__ __forceinline__ void gload_lds16(const void* g, void* l) {
  __builtin_amdgcn_global_load_lds((const __attribute__((address_space(1))) u32*)g,
                                   (__attribute__((address_space(3))) u32*)l,
                                   16, 0, 0);
}

__device__ __forceinline__ u32 pack_f16(float a, float b) {
  auto h2 = __builtin_amdgcn_cvt_pkrtz(a, b);   // __fp16 ext_vector(2)
  return __builtin_bit_cast(u32, h2);
}

__device__ __forceinline__ float max3f(float a, float b, float c) {
  return fmaxf(fmaxf(a, b), c);   // clang fuses to v_max3_f32
}

// ---------------------------------------------------------------- mask dtype probe
__global__ void detect_mask(const u32* __restrict__ m, int* __restrict__ flag) {
  __shared__ int bad;
  if (threadIdx.x == 0) bad = 0;
  __syncthreads();
  int v = 0;
  for (int i = threadIdx.x; i < 1024; i += 256) {
    u32 w = m[i];
    if (w != 0u && w != 1u && w != 0x3F800000u) v = 1;
  }
  if (v) atomicOr(&bad, 1);
  __syncthreads();
  if (threadIdx.x == 0) *flag = bad;   // 1 => byte mask, 0 => 4-byte mask
}

// ---------------------------------------------------------------- phase table
// cos/sin per (b,n,j<32), with rope_mask folded in (masked-off rows -> c=1,s=0
// so downstream applies rope unconditionally; identity is exact via fma).
__global__ __launch_bounds__(256) void phase_tab(const float* __restrict__ px,
                                                 const float* __restrict__ py,
                                                 const float* __restrict__ psp,
                                                 const void* __restrict__ maskPtr,
                                                 const int* __restrict__ maskFlag,
                                                 float* __restrict__ cs_tab,
                                                 float* __restrict__ sn_tab) {
  const int idx = blockIdx.x * 256 + threadIdx.x;   // (b*N+n)*32 + j
  const int j = idx & 31, tn = idx >> 5;
  const int byteMode = *maskFlag;
  const bool doRope = byteMode ? (((const unsigned char*)maskPtr)[tn] != 0)
                               : (((const u32*)maskPtr)[tn] != 0u);
  float c = 1.f, s = 0.f;
  if (doRope) {
    float ph;
    if (j < 12)      ph = px[tn * 12 + j];
    else if (j < 24) ph = py[tn * 12 + (j - 12)];
    else             ph = psp[tn * 8 + (j - 24)];
    c = __cosf(ph);
    s = __sinf(ph);
  }
  cs_tab[idx] = c;
  sn_tab[idx] = s;
}

// ---------------------------------------------------------------- x f32 -> f16
__global__ __launch_bounds__(256) void cvt_x(const float* __restrict__ in,
                                             f16* __restrict__ out, int n8) {
  const int i = blockIdx.x * 256 + threadIdx.x;
  if (i >= n8) return;
  const float4 a = ((const float4*)in)[i * 2];
  const float4 b = ((const float4*)in)[i * 2 + 1];
  f16x8 o = {(f16)a.x, (f16)a.y, (f16)a.z, (f16)a.w,
             (f16)b.x, (f16)b.y, (f16)b.z, (f16)b.w};
  ((f16x8*)out)[i] = o;
}

// ---------------------------------------------------------------- W (RxC f32) -> Wt (CxR f16)
__global__ __launch_bounds__(256) void transpose_cvt(const float* __restrict__ W,
                                                     f16* __restrict__ Wt,
                                                     int R, int Ccols) {
  __shared__ __align__(16) f16 tile[32][34];
  const int c0 = blockIdx.x * 32, r0 = blockIdx.y * 32;
  const int tx = threadIdx.x, ty = threadIdx.y;  // 32 x 8
#pragma unroll
  for (int k = 0; k < 4; ++k)
    tile[ty + 8 * k][tx] = (f16)W[(size_t)(r0 + ty + 8 * k) * Ccols + c0 + tx];
  __syncthreads();
#pragma unroll
  for (int k = 0; k < 4; ++k)
    Wt[(size_t)(c0 + ty + 8 * k) * R + r0 + tx] = tile[tx][ty + 8 * k];
}

// ---------------------------------------------------------------- GEMM  C = A(MxK) * Bt(NxK)^T + bias
template <bool OUT_F32>
__global__ __launch_bounds__(256) void gemm_bt(const f16* __restrict__ A,
                                               const f16* __restrict__ Bt,
                                               const float* __restrict__ bias,
                                               void* __restrict__ Cout,
                                               int M, int N, int K) {
  __shared__ __align__(16) f16 As[128 * 64];
  __shared__ __align__(16) f16 Bs[128 * 64];
  const int tid = threadIdx.x;
  const int lane = tid & 63;
  const int wv = tid >> 6;
  const int wm = wv >> 1, wn = wv & 1;
  const int nTN = N >> 7;
  int bid = blockIdx.x;
  const int cpx = gridDim.x >> 3;
  bid = (bid & 7) * cpx + (bid >> 3);
  const int tM = bid / nTN, tN = bid % nTN;
  const int rowBase = tM << 7, colBase = tN << 7;
  const int cl = lane & 15, cg = lane >> 4;

  f32x4 acc[4][4];
#pragma unroll
  for (int i = 0; i < 4; ++i)
#pragma unroll
    for (int j = 0; j < 4; ++j) acc[i][j] = (f32x4){0.f, 0.f, 0.f, 0.f};

  const int sR = tid >> 3, sC = tid & 7;

  for (int k0 = 0; k0 < K; k0 += 64) {
#pragma unroll
    for (int is = 0; is < 4; ++is) {
      const int r = is * 32 + sR;
      const int sc = sC ^ (r & 7);
      gload_lds16(A + (size_t)(rowBase + r) * K + k0 + sc * 8, As + is * 2048 + tid * 8);
    }
#pragma unroll
    for (int is = 0; is < 4; ++is) {
      const int r = is * 32 + sR;
      const int sc = sC ^ (r & 7);
      gload_lds16(Bt + (size_t)(colBase + r) * K + k0 + sc * 8, Bs + is * 2048 + tid * 8);
    }
    asm volatile("s_waitcnt vmcnt(0)" ::: "memory");
    __syncthreads();

#pragma unroll
    for (int ks = 0; ks < 2; ++ks) {
      f16x8 af[4], bf[4];
#pragma unroll
      for (int m = 0; m < 4; ++m) {
        const int row = wm * 64 + m * 16 + cl;
        const int ck = (ks * 4 + cg) ^ (row & 7);
        af[m] = *(const f16x8*)(As + row * 64 + ck * 8);
      }
#pragma unroll
      for (int n = 0; n < 4; ++n) {
        const int row = wn * 64 + n * 16 + cl;
        const int ck = (ks * 4 + cg) ^ (row & 7);
        bf[n] = *(const f16x8*)(Bs + row * 64 + ck * 8);
      }
#pragma unroll
      for (int m = 0; m < 4; ++m)
#pragma unroll
        for (int n = 0; n < 4; ++n)
          acc[m][n] = __builtin_amdgcn_mfma_f32_16x16x32_f16(af[m], bf[n], acc[m][n], 0, 0, 0);
    }
    __syncthreads();
  }

#pragma unroll
  for (int m = 0; m < 4; ++m) {
#pragma unroll
    for (int n = 0; n < 4; ++n) {
      const int gr0 = rowBase + wm * 64 + m * 16 + cg * 4;
      const int gc = colBase + wn * 64 + n * 16 + cl;
      const float bz = bias[gc];
#pragma unroll
      for (int reg = 0; reg < 4; ++reg) {
        const float v = acc[m][n][reg] + bz;
        if (OUT_F32)
          ((float*)Cout)[(size_t)(gr0 + reg) * N + gc] = v;
        else
          ((f16*)Cout)[(size_t)(gr0 + reg) * N + gc] = (f16)v;
      }
    }
  }
}

// ---------------------------------------------------------------- RoPE + split (table-driven, no trig/mask)
__global__ __launch_bounds__(256) void rope_split(const f16* __restrict__ qkv,
                                                  const float* __restrict__ cs_tab,
                                                  const float* __restrict__ sn_tab,
                                                  f16* __restrict__ Qh,
                                                  f16* __restrict__ Kh,
                                                  f16* __restrict__ Vt) {
  __shared__ float cs[64][32], sn[64][32];
  __shared__ __align__(16) f16 vtile[64][72];
  const int tid = threadIdx.x;
  const int blk = blockIdx.x;
  const int hg = blk & 3;
  const int nt = (blk >> 2) & 31;
  const int b = blk >> 7;
  const int n0 = nt * 64;

  for (int i = tid; i < 64 * 32; i += 256) {
    const int tk = i >> 5, j = i & 31;
    const size_t gi = ((size_t)b * N_ + n0 + tk) * 32 + j;
    cs[tk][j] = cs_tab[gi];
    sn[tk][j] = sn_tab[gi];
  }
  __syncthreads();

  const int tk = tid >> 2, hl = tid & 3;
  const int h = hg * 4 + hl;
  const int n = n0 + tk;
  const size_t inRow = ((size_t)b * N_ + n) * 3072 + (size_t)h * 64;
  const size_t outRow = (((size_t)(b * H_ + h)) * N_ + n) * 64;

#pragma unroll
  for (int sec = 0; sec < 2; ++sec) {
    const f16* src = qkv + inRow + sec * 1024;
    float t[64];
#pragma unroll
    for (int c = 0; c < 8; ++c) {
      f16x8 v = *(const f16x8*)(src + c * 8);
#pragma unroll
      for (int j = 0; j < 8; ++j) t[c * 8 + j] = (float)v[j];
    }
    __align__(16) f16 o[64];
#pragma unroll
    for (int d = 0; d < 64; ++d) {
      int j;
      float rot;
      if (d < 24) {
        j = (d < 12) ? d : d - 12;
        rot = (d < 12) ? -t[d + 12] : t[d - 12];
      } else if (d < 48) {
        const int dd = d - 24;
        j = 12 + ((dd < 12) ? dd : dd - 12);
        rot = (dd < 12) ? -t[d + 12] : t[d - 12];
      } else {
        const int dd = d - 48;
        j = 24 + ((dd < 8) ? dd : dd - 8);
        rot = (dd < 8) ? -t[d + 8] : t[d - 8];
      }
      o[d] = (f16)(t[d] * cs[tk][j] + rot * sn[tk][j]);
    }
    f16* dst = (sec == 0 ? Qh : Kh) + outRow;
#pragma unroll
    for (int c = 0; c < 8; ++c) *(f16x8*)(dst + c * 8) = *(const f16x8*)(o + c * 8);
  }

  for (int hl2 = 0; hl2 < 4; ++hl2) {
    const int h2 = hg * 4 + hl2;
    __syncthreads();
    {
      const int tk2 = tid >> 2, c2 = tid & 3;
      const size_t srow = ((size_t)b * N_ + n0 + tk2) * 3072 + 2048 + (size_t)h2 * 64 + c2 * 16;
      *(f16x8*)(&vtile[tk2][c2 * 16]) = *(const f16x8*)(qkv + srow);
      *(f16x8*)(&vtile[tk2][c2 * 16 + 8]) = *(const f16x8*)(qkv + srow + 8);
    }
    __syncthreads();
    {
      const int d = tid >> 2, seg = tid & 3;
      __align__(16) f16 tmp[16];
#pragma unroll
      for (int i = 0; i < 16; ++i) tmp[i] = vtile[seg * 16 + i][d];
      const size_t drow = (((size_t)(b * H_ + h2)) * 64 + d) * N_ + n0 + seg * 16;
      *(f16x8*)(Vt + drow) = *(const f16x8*)(tmp);
      *(f16x8*)(Vt + drow + 8) = *(const f16x8*)(tmp + 8);
    }
  }
}

// ---------------------------------------------------------------- flash attention v3
// r9 structure; ILP reorder: QK^T for BOTH 32-key chunks first (MFMA overlaps
// chunk-0 softmax VALU), then SM0 -> PV0 -> SM1 -> PV1 (PV0 must precede SM1's
// rescale for online-softmax correctness).
__global__ __launch_bounds__(256) void attn2(const f16* __restrict__ Qh,
                                             const f16* __restrict__ Kh,
                                             const f16* __restrict__ Vt,
                                             f16* __restrict__ Y) {
  __shared__ __align__(16) f16 lds[2][2][4096];  // [buf][K/V][64*64]
  const int tid = threadIdx.x, lane = tid & 63, w = tid >> 6;
  int bid = blockIdx.x;
  bid = (bid & 7) * 64 + (bid >> 3);  // XCD-chunked swizzle (512 % 8 == 0)
  const int bh = bid >> 4, qb = bid & 15;
  const int b = bh >> 4, h = bh & 15;
  const f16* Qb = Qh + (size_t)bh * N_ * 64;
  const f16* Kb = Kh + (size_t)bh * N_ * 64;
  const f16* Vb = Vt + (size_t)bh * 64 * N_;
  const int ql = lane & 31, hi = lane >> 5;

  f16x8 qf[4];
  {
    const int qrow = qb * 128 + w * 32 + ql;
    const f16 scl = (f16)0.125f;
#pragma unroll
    for (int ks = 0; ks < 4; ++ks) {
      f16x8 v = *(const f16x8*)(Qb + (size_t)qrow * 64 + ks * 16 + hi * 8);
#pragma unroll
      for (int j = 0; j < 8; ++j) v[j] *= scl;
      qf[ks] = v;
    }
  }

  f32x16 Of[2];
#pragma unroll
  for (int d = 0; d < 2; ++d)
#pragma unroll
    for (int r = 0; r < 16; ++r) Of[d][r] = 0.f;
  float m_run = -1e30f, l_run = 0.f;

  const int sr = tid >> 3, sc = tid & 7;
#define STAGE(t, bb)                                                                     \
  {                                                                                      \
    _Pragma("unroll") for (int i = 0; i < 2; ++i) {                                      \
      const int row = i * 32 + sr;                                                       \
      const int g = sc ^ (row & 7);                                                      \
      gload_lds16(Kb + (size_t)((t) * 64 + row) * 64 + g * 8,                            \
                  &lds[bb][0][i * 2048 + tid * 8]);                                      \
    }                                                                                    \
    _Pragma("unroll") for (int i = 0; i < 2; ++i) {                                      \
      const int row = i * 32 + sr;                                                       \
      const int g = sc ^ (row & 7);                                                      \
      gload_lds16(Vb + (size_t)row * N_ + (t) * 64 + g * 8,                              \
                  &lds[bb][1][i * 2048 + tid * 8]);                                      \
    }                                                                                    \
  }

// softmax for one 32-key chunk: sa (in/out -> P values), updates m_run/l_run/Of
#define SOFTMAX_CHUNK(sa)                                                                \
  {                                                                                      \
    float t0 = max3f(sa[0], sa[1], sa[2]);                                               \
    float t1 = max3f(sa[3], sa[4], sa[5]);                                               \
    float t2 = max3f(sa[6], sa[7], sa[8]);                                               \
    float t3 = max3f(sa[9], sa[10], sa[11]);                                             \
    float t4 = max3f(sa[12], sa[13], sa[14]);                                            \
    float pmax = max3f(max3f(t0, t1, t2), max3f(t3, t4, sa[15]), -1e30f);                \
    pmax = fmaxf(pmax, __shfl_xor(pmax, 32));                                            \
    if (__any(pmax > m_run + 8.0f)) {                                                    \
      const float mnew = fmaxf(m_run, pmax);                                             \
      const float corr = __expf(m_run - mnew);                                           \
      l_run *= corr;                                                                     \
      _Pragma("unroll") for (int d = 0; d < 2; ++d)                                      \
        _Pragma("unroll") for (int r = 0; r < 16; ++r) Of[d][r] *= corr;                 \
      m_run = mnew;                                                                      \
    }                                                                                    \
    _Pragma("unroll") for (int r = 0; r < 16; ++r) sa[r] = __expf(sa[r] - m_run);        \
    float s0 = ((sa[0] + sa[1]) + (sa[2] + sa[3])) + ((sa[4] + sa[5]) + (sa[6] + sa[7]));\
    float s1 = ((sa[8] + sa[9]) + (sa[10] + sa[11])) +                                   \
               ((sa[12] + sa[13]) + (sa[14] + sa[15]));                                  \
    float ssum = s0 + s1;                                                                \
    ssum += __shfl_xor(ssum, 32);                                                        \
    l_run += ssum;                                                                       \
  }

// PV for one chunk: pack sa -> f16, permlane re-pair, 2 MFMA accumulate into Of
#define PV_CHUNK(sa, s)                                                                  \
  {                                                                                      \
    u32 pw[8];                                                                           \
    _Pragma("unroll") for (int tt = 0; tt < 8; ++tt)                                     \
      pw[tt] = pack_f16(sa[2 * tt], sa[2 * tt + 1]);                                     \
    _Pragma("unroll") for (int kk = 0; kk < 2; ++kk) {                                   \
      u32 a0 = pw[4 * kk], a1 = pw[4 * kk + 1];                                          \
      u32 b0 = pw[4 * kk + 2], b1 = pw[4 * kk + 3];                                      \
      asm volatile("v_permlane32_swap_b32 %0, %1" : "+v"(a0), "+v"(b0));                 \
      asm volatile("v_permlane32_swap_b32 %0, %1" : "+v"(a1), "+v"(b1));                 \
      union { u32 u[4]; f16x8 v; } pf;                                                   \
      pf.u[0] = a0; pf.u[1] = a1; pf.u[2] = b0; pf.u[3] = b1;                            \
      __builtin_amdgcn_s_setprio(1);                                                     \
      _Pragma("unroll") for (int df = 0; df < 2; ++df) {                                 \
        const int d = df * 32 + ql;                                                      \
        f16x8 vf = *(const f16x8*)(Vs + d * 64 + (((s) * 4 + kk * 2 + hi) ^ (d & 7)) * 8);\
        Of[df] = __builtin_amdgcn_mfma_f32_32x32x16_f16(vf, pf.v, Of[df], 0, 0, 0);      \
      }                                                                                  \
      __builtin_amdgcn_s_setprio(0);                                                     \
    }                                                                                    \
  }

  STAGE(0, 0);
  asm volatile("s_waitcnt vmcnt(0)" ::: "memory");
  __syncthreads();

  int cur = 0;
  for (int t = 0; t < N_ / 64; ++t) {
    if (t < N_ / 64 - 1) STAGE(t + 1, cur ^ 1);
    const f16* Ks = &lds[cur][0][0];
    const f16* Vs = &lds[cur][1][0];

    // ---- QK^T for both chunks (8 MFMA); chunk-1 MFMAs overlap chunk-0 softmax
    f32x16 sa0, sa1;
#pragma unroll
    for (int r = 0; r < 16; ++r) { sa0[r] = 0.f; sa1[r] = 0.f; }
    const int krow0 = ql, krow1 = 32 + ql;
    __builtin_amdgcn_s_setprio(1);
#pragma unroll
    for (int ks = 0; ks < 4; ++ks) {
      f16x8 kf = *(const f16x8*)(Ks + krow0 * 64 + ((ks * 2 + hi) ^ (krow0 & 7)) * 8);
      sa0 = __builtin_amdgcn_mfma_f32_32x32x16_f16(kf, qf[ks], sa0, 0, 0, 0);
    }
#pragma unroll
    for (int ks = 0; ks < 4; ++ks) {
      f16x8 kf = *(const f16x8*)(Ks + krow1 * 64 + ((ks * 2 + hi) ^ (krow1 & 7)) * 8);
      sa1 = __builtin_amdgcn_mfma_f32_32x32x16_f16(kf, qf[ks], sa1, 0, 0, 0);
    }
    __builtin_amdgcn_s_setprio(0);

    SOFTMAX_CHUNK(sa0);
    PV_CHUNK(sa0, 0);
    SOFTMAX_CHUNK(sa1);
    PV_CHUNK(sa1, 1);

    asm volatile("s_waitcnt vmcnt(0)" ::: "memory");
    __syncthreads();
    cur ^= 1;
  }

  // ---- epilogue: O^T regs -> LDS transpose -> coalesced f16 stores
  const float inv = 1.0f / l_run;
  f16* Ow = &lds[0][0][0] + w * (32 * 72);
#pragma unroll
  for (int df = 0; df < 2; ++df)
#pragma unroll
    for (int g = 0; g < 4; ++g) {
      f16x4 ov;
#pragma unroll
      for (int e = 0; e < 4; ++e) ov[e] = (f16)(Of[df][g * 4 + e] * inv);
      *(f16x4*)(Ow + ql * 72 + df * 32 + g * 8 + hi * 4) = ov;
    }
  __syncthreads();
  const int rr = lane >> 1, half = lane & 1;
  const f16* srcp = Ow + rr * 72 + half * 32;
  const int nglob = qb * 128 + w * 32 + rr;
  f16* dst = Y + ((size_t)b * N_ + nglob) * C_ + h * 64 + half * 32;
#pragma unroll
  for (int c2 = 0; c2 < 4; ++c2)
    *(f16x8*)(dst + c2 * 8) = *(const f16x8*)(srcp + c2 * 8);
}

// ---------------------------------------------------------------- launch
extern "C" void kernel_launch(void* const* d_in, const int* in_sizes, int n_in,
                              void* d_out, int out_size, void* d_ws, size_t ws_size,
                              hipStream_t stream) {
  const float* x = (const float*)d_in[0];
  const float* px = (const float*)d_in[1];
  const float* py = (const float*)d_in[2];
  const float* psp = (const float*)d_in[3];
  const void* mask = (const void*)d_in[4];
  const float* Wqkv = (const float*)d_in[5];
  const float* bqkv = (const float*)d_in[6];
  const float* Wproj = (const float*)d_in[7];
  const float* bproj = (const float*)d_in[8];
  float* out = (float*)d_out;
  char* ws = (char*)d_ws;

  f16* xh     = (f16*)(ws + 0);           //  8,388,608
  f16* Wqkvt  = (f16*)(ws + 8388608);     //  6,291,456
  f16* Wprojt = (f16*)(ws + 14680064);    //  2,097,152
  f16* qkvh   = (f16*)(ws + 16777216);    // 25,165,824
  f16* Qh     = (f16*)(ws + 41943040);    //  8,388,608
  f16* Kh     = (f16*)(ws + 50331648);    //  8,388,608
  f16* Vt     = (f16*)(ws + 58720256);    //  8,388,608
  f16* Yh     = (f16*)(ws + 67108864);    //  8,388,608
  int* mflag  = (int*)(ws + 75497472);    //  4
  // phase tables live in the (currently dead) Yh region: written by phase_tab,
  // read by rope_split, both BEFORE attn2 overwrites Yh. Stream-ordered, safe.
  float* cs_tab = (float*)(ws + 67108864);            // 524,288
  float* sn_tab = (float*)(ws + 67108864 + 524288);   // 524,288

  detect_mask<<<1, 256, 0, stream>>>((const u32*)mask, mflag);
  cvt_x<<<2048, 256, 0, stream>>>(x, xh, (B_ * N_ * C_) / 8);
  phase_tab<<<512, 256, 0, stream>>>(px, py, psp, mask, mflag, cs_tab, sn_tab);
  transpose_cvt<<<dim3(96, 32), dim3(32, 8), 0, stream>>>(Wqkv, Wqkvt, C_, 3 * C_);
  transpose_cvt<<<dim3(32, 32), dim3(32, 8), 0, stream>>>(Wproj, Wprojt, C_, C_);
  gemm_bt<false><<<(4096 / 128) * (3072 / 128), 256, 0, stream>>>(
      xh, Wqkvt, bqkv, (void*)qkvh, 4096, 3072, 1024);
  rope_split<<<256, 256, 0, stream>>>(qkvh, cs_tab, sn_tab, Qh, Kh, Vt);
  attn2<<<512, 256, 0, stream>>>(Qh, Kh, Vt, Yh);
  gemm_bt<true><<<(4096 / 128) * (1024 / 128), 256, 0, stream>>>(
      Yh, Wprojt, bproj, (void*)out, 4096, 1024, 1024);
}